// Round 4
// baseline (625.239 us; speedup 1.0000x reference)
//
#include <hip/hip_runtime.h>
#include <hip/hip_bf16.h>
#include <cmath>

#define NROW 2048      // B*S
#define DMODEL 512
#define FIN 240
#define FINPAD 256
#define NHEAD 16
#define DHEAD 32
#define CHUNK 64
#define NCHUNK 16      // S / CHUNK
#define NLAYER 6
#define SEQ 1024
#define QKVLD 1536

typedef __attribute__((ext_vector_type(8))) short bf16x8;
typedef __attribute__((ext_vector_type(4))) float f32x4;

// phi(x) = elu(x) + 1
__device__ __forceinline__ float phi(float x) {
    return x > 0.f ? x + 1.f : expf(x);
}

// ---------------- LayerNorm (optional residual add, fp32 and/or bf16 out) --
// one block per row, 256 threads; C <= 512, Cpad <= 512
__global__ __launch_bounds__(256) void ln_kernel(
    const float* __restrict__ in, const float* __restrict__ res,
    const float* __restrict__ g, const float* __restrict__ b,
    float* __restrict__ out, __hip_bfloat16* __restrict__ outb,
    int C, int Cpad) {
    int row = blockIdx.x;
    int tid = threadIdx.x;
    const float* xr = in + (size_t)row * C;
    const float* rr = res ? res + (size_t)row * C : nullptr;
    float vals[2];
    float sum = 0.f, sq = 0.f;
#pragma unroll
    for (int i = 0; i < 2; ++i) {
        int c = tid + i * 256;
        float v = 0.f;
        if (c < C) { v = xr[c]; if (rr) v += rr[c]; }
        vals[i] = v;
        sum += v; sq += v * v;
    }
#pragma unroll
    for (int off = 32; off > 0; off >>= 1) {
        sum += __shfl_xor(sum, off, 64);
        sq  += __shfl_xor(sq,  off, 64);
    }
    __shared__ float red[8];
    int wv = tid >> 6, ln = tid & 63;
    if (ln == 0) { red[wv] = sum; red[4 + wv] = sq; }
    __syncthreads();
    sum = red[0] + red[1] + red[2] + red[3];
    sq  = red[4] + red[5] + red[6] + red[7];
    float mean = sum / (float)C;
    float var  = sq / (float)C - mean * mean;
    float rstd = rsqrtf(var + 1e-5f);
#pragma unroll
    for (int i = 0; i < 2; ++i) {
        int c = tid + i * 256;
        float y = (vals[i] - mean) * rstd;
        if (c < C) {
            y = y * g[c] + b[c];
            if (out) out[(size_t)row * C + c] = y;
        }
        if (outb && c < Cpad)
            outb[(size_t)row * Cpad + c] = __float2bfloat16(c < C ? y : 0.f);
    }
}

// ---------------- bf16 MFMA GEMM, LDS-free: C = A[M,K] * Bt[N,K]^T + bias --
// Block = 64x64 tile, 4 waves 2x2, wave tile 32x32 (2x2 frags).
// Operands loaded global->VGPR directly in MFMA fragment layout (16B/lane),
// no LDS, no barriers, no bank conflicts. 1-deep register prefetch.
// 1-D grid with XCD-aware swizzle (n-fastest decode within each XCD chunk).
template<int RELU, int WF32, int WBF16>
__global__ __launch_bounds__(256, 4) void gemm_bf16_kernel(
    const __hip_bfloat16* __restrict__ A, const __hip_bfloat16* __restrict__ Bt,
    const float* __restrict__ bias,
    float* __restrict__ C, __hip_bfloat16* __restrict__ Cb,
    int M, int N, int K, int nN) {
    int tid = threadIdx.x;
    int lane = tid & 63, w = tid >> 6;
    // XCD swizzle: consecutive hardware ids round-robin XCDs; give each XCD a
    // contiguous wg chunk; decode wg with n fastest so a chunk = few A-row
    // panels x all N (A slice stays in that XCD's L2).
    int G = gridDim.x;
    int id = blockIdx.x;
    int wg = (id & 7) * (G >> 3) + (id >> 3);
    int nb = wg % nN, mb = wg / nN;
    int bm = mb * 64, bn = nb * 64;
    int wm = (w >> 1) << 5, wn = (w & 1) << 5;
    int fr = lane & 15, kg = (lane >> 4) << 3;   // frag row/col, k-offset (elems)

    const __hip_bfloat16* pa0 = A  + (size_t)(bm + wm + fr) * K + kg;
    const __hip_bfloat16* pa1 = pa0 + (size_t)16 * K;
    const __hip_bfloat16* pb0 = Bt + (size_t)(bn + wn + fr) * K + kg;
    const __hip_bfloat16* pb1 = pb0 + (size_t)16 * K;

    f32x4 acc00 = {0.f, 0.f, 0.f, 0.f}, acc01 = acc00, acc10 = acc00, acc11 = acc00;

    bf16x8 a0 = *(const bf16x8*)pa0;
    bf16x8 a1 = *(const bf16x8*)pa1;
    bf16x8 b0 = *(const bf16x8*)pb0;
    bf16x8 b1 = *(const bf16x8*)pb1;
    for (int k0 = 0; k0 < K; k0 += 32) {
        bf16x8 na0, na1, nb0, nb1;
        int kn = k0 + 32;
        if (kn < K) {
            na0 = *(const bf16x8*)(pa0 + kn);
            na1 = *(const bf16x8*)(pa1 + kn);
            nb0 = *(const bf16x8*)(pb0 + kn);
            nb1 = *(const bf16x8*)(pb1 + kn);
        }
        acc00 = __builtin_amdgcn_mfma_f32_16x16x32_bf16(a0, b0, acc00, 0, 0, 0);
        acc01 = __builtin_amdgcn_mfma_f32_16x16x32_bf16(a0, b1, acc01, 0, 0, 0);
        acc10 = __builtin_amdgcn_mfma_f32_16x16x32_bf16(a1, b0, acc10, 0, 0, 0);
        acc11 = __builtin_amdgcn_mfma_f32_16x16x32_bf16(a1, b1, acc11, 0, 0, 0);
        a0 = na0; a1 = na1; b0 = nb0; b1 = nb1;
    }

    int orow = bm + wm + ((lane >> 4) << 2);
    int ocol = bn + wn + (lane & 15);
    float bv0 = bias[ocol], bv1 = bias[ocol + 16];
#pragma unroll
    for (int r = 0; r < 4; ++r) {
        float v00 = acc00[r] + bv0;
        float v01 = acc01[r] + bv1;
        float v10 = acc10[r] + bv0;
        float v11 = acc11[r] + bv1;
        if (RELU) {
            v00 = fmaxf(v00, 0.f); v01 = fmaxf(v01, 0.f);
            v10 = fmaxf(v10, 0.f); v11 = fmaxf(v11, 0.f);
        }
        if (WF32) {
            C[(size_t)(orow + r) * N + ocol]           = v00;
            C[(size_t)(orow + r) * N + ocol + 16]      = v01;
            C[(size_t)(orow + 16 + r) * N + ocol]      = v10;
            C[(size_t)(orow + 16 + r) * N + ocol + 16] = v11;
        }
        if (WBF16) {
            Cb[(size_t)(orow + r) * N + ocol]           = __float2bfloat16(v00);
            Cb[(size_t)(orow + r) * N + ocol + 16]      = __float2bfloat16(v01);
            Cb[(size_t)(orow + 16 + r) * N + ocol]      = __float2bfloat16(v10);
            Cb[(size_t)(orow + 16 + r) * N + ocol + 16] = __float2bfloat16(v11);
        }
    }
}

// ---------------- weight transpose + bf16 convert ---------------------------
// src fp32 [K][512] -> dst bf16 [512][Kpad] (zero-padded k>=K); 64x64 tiles
__global__ __launch_bounds__(256) void wconv_kernel(
    const float* __restrict__ W_pre, const float* __restrict__ Wq,
    const float* __restrict__ Wk, const float* __restrict__ Wv,
    const float* __restrict__ Wo, const float* __restrict__ W1,
    const float* __restrict__ W2, const float* __restrict__ W_post,
    __hip_bfloat16* wpre_t, __hip_bfloat16* wqkv_t, __hip_bfloat16* wo_t,
    __hip_bfloat16* w1_t, __hip_bfloat16* w2_t, __hip_bfloat16* wpost_t) {
    __shared__ float tile[64][65];
    int tb = blockIdx.x;
    const float* src; __hip_bfloat16* dst; int K, Kpad, kt, nt;
    if (tb < 32) {
        src = W_pre; dst = wpre_t; K = FIN; Kpad = FINPAD;
        kt = tb >> 3; nt = tb & 7;
    } else {
        int t2 = tb - 32; int mat = t2 >> 6; int tt = t2 & 63;
        kt = tt >> 3; nt = tt & 7; K = 512; Kpad = 512;
        if (mat == 36) { src = W_post; dst = wpost_t; }
        else {
            int l = mat / 6, j = mat % 6;
            const size_t WSZ = 262144;
            switch (j) {
                case 0: src = Wq + l * WSZ; dst = wqkv_t + l * 786432;          break;
                case 1: src = Wk + l * WSZ; dst = wqkv_t + l * 786432 + 262144; break;
                case 2: src = Wv + l * WSZ; dst = wqkv_t + l * 786432 + 524288; break;
                case 3: src = Wo + l * WSZ; dst = wo_t + l * WSZ;               break;
                case 4: src = W1 + l * WSZ; dst = w1_t + l * WSZ;               break;
                default: src = W2 + l * WSZ; dst = w2_t + l * WSZ;              break;
            }
        }
    }
    const int N = 512;
    int t = threadIdx.x;
    int k0 = kt * 64, n0 = nt * 64;
#pragma unroll
    for (int i = 0; i < 16; ++i) {
        int kk = (t >> 6) * 16 + i;
        int nn = t & 63;
        int k = k0 + kk;
        tile[kk][nn] = (k < K) ? src[(size_t)k * N + n0 + nn] : 0.f;
    }
    __syncthreads();
#pragma unroll
    for (int i = 0; i < 16; ++i) {
        int nn = (t >> 6) * 16 + i;
        int kk = t & 63;
        dst[(size_t)(n0 + nn) * Kpad + k0 + kk] = __float2bfloat16(tile[kk][nn]);
    }
}

__global__ void bias_concat_kernel(const float* __restrict__ bq,
                                   const float* __restrict__ bk,
                                   const float* __restrict__ bv,
                                   float* __restrict__ o) {
    int l = blockIdx.x, t = threadIdx.x;  // 512 threads
    o[l * QKVLD + t]        = bq[l * DMODEL + t];
    o[l * QKVLD + 512 + t]  = bk[l * DMODEL + t];
    o[l * QKVLD + 1024 + t] = bv[l * DMODEL + t];
}

// ---------------- attention phase A: per-chunk K^T V sums + K column sums --
// grid (NCHUNK, NHEAD, B), 256 threads; k,v row stride ld
__global__ __launch_bounds__(256) void attn_sums_kernel(
    const float* __restrict__ k, const float* __restrict__ v, int ld,
    float* __restrict__ kvsum, float* __restrict__ ksum) {
    __shared__ float Ks[CHUNK][33];
    __shared__ float Vs[CHUNK][33];
    int c = blockIdx.x, hh = blockIdx.y, b = blockIdx.z;
    int tid = threadIdx.x;
    size_t base = ((size_t)(b * SEQ + c * CHUNK)) * ld + hh * DHEAD;
#pragma unroll
    for (int i = 0; i < 8; ++i) {
        int s = (tid >> 5) + i * 8;
        int d = tid & 31;
        Ks[s][d] = phi(k[base + (size_t)s * ld + d]);
        Vs[s][d] = v[base + (size_t)s * ld + d];
    }
    __syncthreads();
    int m = tid & 31;
    float acc[4] = {0.f, 0.f, 0.f, 0.f};
    for (int s = 0; s < CHUNK; ++s) {
        float vm = Vs[s][m];
#pragma unroll
        for (int i = 0; i < 4; ++i)
            acc[i] = fmaf(Ks[s][(tid >> 5) + 8 * i], vm, acc[i]);
    }
    size_t ob = ((size_t)((b * NHEAD + hh) * NCHUNK + c)) * (DHEAD * DHEAD);
#pragma unroll
    for (int i = 0; i < 4; ++i)
        kvsum[ob + (size_t)((tid >> 5) + 8 * i) * DHEAD + m] = acc[i];
    if (tid < 32) {
        float s_ = 0.f;
        for (int s = 0; s < CHUNK; ++s) s_ += Ks[s][tid];
        ksum[((size_t)((b * NHEAD + hh) * NCHUNK + c)) * DHEAD + tid] = s_;
    }
}

// ---------------- attention phase B: exclusive scan over chunks ------------
__global__ __launch_bounds__(1024) void attn_scan_kernel(
    const float* __restrict__ kvsum, const float* __restrict__ ksum,
    float* __restrict__ state, float* __restrict__ kstate) {
    int bh = blockIdx.x;
    int tid = threadIdx.x;
    size_t base = (size_t)bh * NCHUNK * (DHEAD * DHEAD);
    float vals[NCHUNK];
#pragma unroll
    for (int c = 0; c < NCHUNK; ++c)
        vals[c] = kvsum[base + (size_t)c * (DHEAD * DHEAD) + tid];
    float run = 0.f;
#pragma unroll
    for (int c = 0; c < NCHUNK; ++c) {
        float nv = vals[c];
        vals[c] = run;
        run += nv;
    }
#pragma unroll
    for (int c = 0; c < NCHUNK; ++c)
        state[base + (size_t)c * (DHEAD * DHEAD) + tid] = vals[c];
    if (tid < 32) {
        size_t kb = (size_t)bh * NCHUNK * DHEAD;
        float kv[NCHUNK];
#pragma unroll
        for (int c = 0; c < NCHUNK; ++c) kv[c] = ksum[kb + c * DHEAD + tid];
        float rk = 0.f;
#pragma unroll
        for (int c = 0; c < NCHUNK; ++c) {
            float nv = kv[c];
            kstate[kb + c * DHEAD + tid] = rk;
            rk += nv;
        }
    }
}

// ---------------- attention phase C: intra-chunk + state application -------
// grid (NCHUNK, NHEAD, B), 256 threads; q,k,v row stride ld; out bf16 stride 512
__global__ __launch_bounds__(256) void attn_out_kernel(
    const float* __restrict__ q, const float* __restrict__ k,
    const float* __restrict__ v, int ld,
    const float* __restrict__ state, const float* __restrict__ kstate,
    __hip_bfloat16* __restrict__ out) {
    __shared__ float Qs[CHUNK][33];
    __shared__ float Ks[CHUNK][33];
    __shared__ float Vs[CHUNK][33];
    __shared__ float St[DHEAD][DHEAD];
    __shared__ float Aw[CHUNK][65];
    __shared__ float den[CHUNK];
    __shared__ float ksml[DHEAD];
    int c = blockIdx.x, hh = blockIdx.y, b = blockIdx.z;
    int tid = threadIdx.x;
    size_t base = ((size_t)(b * SEQ + c * CHUNK)) * ld + hh * DHEAD;
#pragma unroll
    for (int i = 0; i < 8; ++i) {
        int s = (tid >> 5) + i * 8;
        int d = tid & 31;
        Qs[s][d] = phi(q[base + (size_t)s * ld + d]);
        Ks[s][d] = phi(k[base + (size_t)s * ld + d]);
        Vs[s][d] = v[base + (size_t)s * ld + d];
    }
    size_t sb = ((size_t)((b * NHEAD + hh) * NCHUNK + c)) * (DHEAD * DHEAD);
#pragma unroll
    for (int i = 0; i < 4; ++i) {
        int idx = tid + i * 256;
        ((float*)St)[idx] = state[sb + idx];
    }
    if (tid < 32)
        ksml[tid] = kstate[((size_t)((b * NHEAD + hh) * NCHUNK + c)) * DHEAD + tid];
    __syncthreads();
#pragma unroll
    for (int i = 0; i < 16; ++i) {
        int s_ = (tid >> 6) + 4 * i;
        int t_ = tid & 63;
        float a_ = 0.f;
        if (t_ <= s_) {
            for (int d = 0; d < DHEAD; ++d)
                a_ = fmaf(Qs[s_][d], Ks[t_][d], a_);
        }
        Aw[s_][t_] = a_;
    }
    __syncthreads();
    if (tid < CHUNK) {
        int s_ = tid;
        float d_ = 0.f;
        for (int d = 0; d < DHEAD; ++d) d_ = fmaf(Qs[s_][d], ksml[d], d_);
        for (int t_ = 0; t_ <= s_; ++t_) d_ += Aw[s_][t_];
        den[s_] = 1.f / (d_ + 1e-6f);
    }
    __syncthreads();
    int m = tid & 31;
    size_t obase = ((size_t)(b * SEQ + c * CHUNK)) * DMODEL + hh * DHEAD;
#pragma unroll
    for (int i = 0; i < 8; ++i) {
        int s_ = (tid >> 5) * 8 + i;
        float o = 0.f;
        for (int d = 0; d < DHEAD; ++d) o = fmaf(Qs[s_][d], St[d][m], o);
        for (int t_ = 0; t_ <= s_; ++t_) o = fmaf(Aw[s_][t_], Vs[t_][m], o);
        out[obase + (size_t)s_ * DMODEL + m] = __float2bfloat16(o * den[s_]);
    }
}

// ---------------------------------------------------------------------------
template<int R, int WF, int WB>
static inline void gemm(const __hip_bfloat16* A, const __hip_bfloat16* Bt,
                        const float* bias, float* C, __hip_bfloat16* Cb,
                        int M, int N, int K, hipStream_t s) {
    int nM = M / 64, nN = N / 64;
    gemm_bf16_kernel<R, WF, WB><<<nM * nN, 256, 0, s>>>(A, Bt, bias, C, Cb, M, N, K, nN);
}

extern "C" void kernel_launch(void* const* d_in, const int* in_sizes, int n_in,
                              void* d_out, int out_size, void* d_ws, size_t ws_size,
                              hipStream_t stream) {
    const float* x      = (const float*)d_in[0];
    const float* g_in   = (const float*)d_in[1];
    const float* b_in   = (const float*)d_in[2];
    const float* W_pre  = (const float*)d_in[3];
    const float* b_pre  = (const float*)d_in[4];
    const float* Wq     = (const float*)d_in[5];
    const float* bq     = (const float*)d_in[6];
    const float* Wk     = (const float*)d_in[7];
    const float* bk     = (const float*)d_in[8];
    const float* Wv     = (const float*)d_in[9];
    const float* bv     = (const float*)d_in[10];
    const float* Wo     = (const float*)d_in[11];
    const float* bo     = (const float*)d_in[12];
    const float* W1     = (const float*)d_in[13];
    const float* bf1    = (const float*)d_in[14];
    const float* W2     = (const float*)d_in[15];
    const float* bf2    = (const float*)d_in[16];
    const float* ln1_g  = (const float*)d_in[17];
    const float* ln1_b  = (const float*)d_in[18];
    const float* ln2_g  = (const float*)d_in[19];
    const float* ln2_b  = (const float*)d_in[20];
    const float* lnf_g  = (const float*)d_in[21];
    const float* lnf_b  = (const float*)d_in[22];
    const float* W_post = (const float*)d_in[23];
    const float* b_post = (const float*)d_in[24];
    (void)in_sizes; (void)n_in; (void)out_size; (void)ws_size;

    float* ws = (float*)d_ws;
    const size_t SZ = (size_t)NROW * DMODEL;          // 1048576
    float* h       = ws;
    float* qkv     = h + SZ;                          // 2048*1536 = 3145728
    float* t1      = qkv + 3145728;
    float* kvsum   = t1 + SZ;                         // 524288
    float* stat    = kvsum + 524288;
    float* ksum    = stat + 524288;                   // 16384
    float* kstate  = ksum + 16384;
    float* qkvbias = kstate + 16384;                  // 6*1536 = 9216
    __hip_bfloat16* bp = (__hip_bfloat16*)(qkvbias + 9216);
    __hip_bfloat16* hb     = bp;            bp += SZ;
    __hip_bfloat16* xnb    = bp;            bp += (size_t)NROW * FINPAD;   // 524288
    __hip_bfloat16* attb   = bp;            bp += SZ;
    __hip_bfloat16* ffb    = bp;            bp += SZ;
    __hip_bfloat16* t0b    = bp;            bp += SZ;
    __hip_bfloat16* wpre_t = bp;            bp += (size_t)DMODEL * FINPAD; // 131072
    __hip_bfloat16* wqkv_t = bp;            bp += (size_t)NLAYER * 786432;
    __hip_bfloat16* wo_t   = bp;            bp += (size_t)NLAYER * 262144;
    __hip_bfloat16* w1_t   = bp;            bp += (size_t)NLAYER * 262144;
    __hip_bfloat16* w2_t   = bp;            bp += (size_t)NLAYER * 262144;
    __hip_bfloat16* wpost_t= bp;

    // one-time-per-call weight conversion (graph-safe, deterministic)
    wconv_kernel<<<32 + 37 * 64, 256, 0, stream>>>(
        W_pre, Wq, Wk, Wv, Wo, W1, W2, W_post,
        wpre_t, wqkv_t, wo_t, w1_t, w2_t, wpost_t);
    bias_concat_kernel<<<NLAYER, 512, 0, stream>>>(bq, bk, bv, qkvbias);

    // input LN (bf16, K padded 240->256) + pre projection (h fp32 + hb bf16)
    ln_kernel<<<NROW, 256, 0, stream>>>(x, nullptr, g_in, b_in, nullptr, xnb, FIN, FINPAD);
    gemm<0, 1, 1>(xnb, wpre_t, b_pre, h, hb, NROW, DMODEL, FINPAD, stream);

    dim3 ag(NCHUNK, NHEAD, 2);
    for (int l = 0; l < NLAYER; ++l) {
        // fused QKV projection -> qkv fp32 [2048][1536]
        gemm<0, 1, 0>(hb, wqkv_t + (size_t)l * 786432, qkvbias + l * QKVLD,
                      qkv, nullptr, NROW, QKVLD, DMODEL, stream);
        const float* qp = qkv;
        const float* kp = qkv + 512;
        const float* vp = qkv + 1024;
        attn_sums_kernel<<<ag, 256, 0, stream>>>(kp, vp, QKVLD, kvsum, ksum);
        attn_scan_kernel<<<32, 1024, 0, stream>>>(kvsum, ksum, stat, kstate);
        attn_out_kernel<<<ag, 256, 0, stream>>>(qp, kp, vp, QKVLD, stat, kstate, attb);
        gemm<0, 1, 0>(attb, wo_t + (size_t)l * 262144, bo + l * DMODEL,
                      t1, nullptr, NROW, DMODEL, DMODEL, stream);
        ln_kernel<<<NROW, 256, 0, stream>>>(h, t1, ln1_g + l * DMODEL, ln1_b + l * DMODEL,
                                            h, hb, DMODEL, DMODEL);
        gemm<1, 0, 1>(hb, w1_t + (size_t)l * 262144, bf1 + l * DMODEL,
                      nullptr, ffb, NROW, DMODEL, DMODEL, stream);
        gemm<0, 1, 0>(ffb, w2_t + (size_t)l * 262144, bf2 + l * DMODEL,
                      t1, nullptr, NROW, DMODEL, DMODEL, stream);
        ln_kernel<<<NROW, 256, 0, stream>>>(h, t1, ln2_g + l * DMODEL, ln2_b + l * DMODEL,
                                            h, hb, DMODEL, DMODEL);
    }

    // final LN (bf16 only) + post projection (fp32 to d_out)
    ln_kernel<<<NROW, 256, 0, stream>>>(h, nullptr, lnf_g, lnf_b, nullptr, t0b, DMODEL, DMODEL);
    gemm<0, 1, 0>(t0b, wpost_t, b_post, (float*)d_out, nullptr, NROW, DMODEL, DMODEL, stream);
}

// Round 5
// 468.909 us; speedup vs baseline: 1.3334x; 1.3334x over previous
//
#include <hip/hip_runtime.h>
#include <hip/hip_bf16.h>
#include <cmath>

#define NROW 2048      // B*S
#define DMODEL 512
#define FIN 240
#define FINPAD 256
#define NHEAD 16
#define DHEAD 32
#define CHUNK 64
#define NCHUNK 16      // S / CHUNK
#define NLAYER 6
#define SEQ 1024
#define QKVLD 1536

typedef __attribute__((ext_vector_type(8))) short bf16x8;
typedef __attribute__((ext_vector_type(4))) float f32x4;

// phi(x) = elu(x) + 1
__device__ __forceinline__ float phi(float x) {
    return x > 0.f ? x + 1.f : expf(x);
}

__device__ __forceinline__ void load_lds16(const void* g, void* l) {
    __builtin_amdgcn_global_load_lds(
        (const __attribute__((address_space(1))) void*)g,
        (__attribute__((address_space(3))) void*)l, 16, 0, 0);
}

// ---------------- LayerNorm (optional residual add, fp32 and/or bf16 out) --
__global__ __launch_bounds__(256) void ln_kernel(
    const float* __restrict__ in, const float* __restrict__ res,
    const float* __restrict__ g, const float* __restrict__ b,
    float* __restrict__ out, __hip_bfloat16* __restrict__ outb,
    int C, int Cpad) {
    int row = blockIdx.x;
    int tid = threadIdx.x;
    const float* xr = in + (size_t)row * C;
    const float* rr = res ? res + (size_t)row * C : nullptr;
    float vals[2];
    float sum = 0.f, sq = 0.f;
#pragma unroll
    for (int i = 0; i < 2; ++i) {
        int c = tid + i * 256;
        float v = 0.f;
        if (c < C) { v = xr[c]; if (rr) v += rr[c]; }
        vals[i] = v;
        sum += v; sq += v * v;
    }
#pragma unroll
    for (int off = 32; off > 0; off >>= 1) {
        sum += __shfl_xor(sum, off, 64);
        sq  += __shfl_xor(sq,  off, 64);
    }
    __shared__ float red[8];
    int wv = tid >> 6, ln = tid & 63;
    if (ln == 0) { red[wv] = sum; red[4 + wv] = sq; }
    __syncthreads();
    sum = red[0] + red[1] + red[2] + red[3];
    sq  = red[4] + red[5] + red[6] + red[7];
    float mean = sum / (float)C;
    float var  = sq / (float)C - mean * mean;
    float rstd = rsqrtf(var + 1e-5f);
#pragma unroll
    for (int i = 0; i < 2; ++i) {
        int c = tid + i * 256;
        float y = (vals[i] - mean) * rstd;
        if (c < C) {
            y = y * g[c] + b[c];
            if (out) out[(size_t)row * C + c] = y;
        }
        if (outb && c < Cpad)
            outb[(size_t)row * Cpad + c] = __float2bfloat16(c < C ? y : 0.f);
    }
}

// ---------------- bf16 MFMA GEMM, counted-vmcnt ring pipeline ---------------
// C = A[M,K] * Bt[N,K]^T + bias. BM=32, BN=64, BK=64, ring of 4 K-step
// buffers resident in LDS (48 KB). global_load_lds staging with pre-swizzled
// global source (16B slot ^= row&7); ds_read uses the same swizzle -> 2-way
// bank conflicts only. s_waitcnt vmcnt(6) (counted, never 0 mid-loop) + raw
// s_barrier per step: loads stay in flight across barriers.
template<int RELU, int WF32, int WBF16, int K>
__global__ __launch_bounds__(256) void gemm_bf16_kernel(
    const __hip_bfloat16* __restrict__ A, const __hip_bfloat16* __restrict__ Bt,
    const float* __restrict__ bias,
    float* __restrict__ C, __hip_bfloat16* __restrict__ Cb,
    int N) {
    constexpr int NSTEP = K / 64;
    __shared__ __align__(16) __hip_bfloat16 As[4][32][64];
    __shared__ __align__(16) __hip_bfloat16 Bs[4][64][64];
    const int tid = threadIdx.x, lane = tid & 63, w = tid >> 6;
    const int nN = N >> 6;
    const int bm = (blockIdx.x / nN) * 32;
    const int bn = (blockIdx.x % nN) * 64;

    // staging: wave w covers 8 rows (w*8 + (lane>>3)); lane slot = lane&7.
    // stored slot s holds global slot s ^ (row&7)  (row&7 == (lane>>3)&7).
    const int srow  = lane >> 3;                 // 0..7
    const int sslot = (lane & 7) ^ srow;         // pre-swizzled global slot
    const size_t aoff = (size_t)srow * K + (size_t)sslot * 8;
    const __hip_bfloat16* gA  = A  + (size_t)(bm + w * 8) * K + aoff;
    const __hip_bfloat16* gB0 = Bt + (size_t)(bn + w * 8) * K + aoff;
    const __hip_bfloat16* gB1 = Bt + (size_t)(bn + 32 + w * 8) * K + aoff;

#define STAGE(t) do { \
        load_lds16(gA  + (size_t)(t) * 64, &As[(t) & 3][w * 8][0]); \
        load_lds16(gB0 + (size_t)(t) * 64, &Bs[(t) & 3][w * 8][0]); \
        load_lds16(gB1 + (size_t)(t) * 64, &Bs[(t) & 3][32 + w * 8][0]); \
    } while (0)

    // wave tile 16x32: waves 2x2 over 32x64
    const int wm = (w >> 1) << 4, wn = (w & 1) << 5;
    const int fr = lane & 15, fq = lane >> 4;    // frag row/col, k-group
    const int sw = fr & 7;
    const int e0 = ((fq      ^ sw) << 3);        // elem offset, k slots 0..3
    const int e1 = (((fq | 4) ^ sw) << 3);       // elem offset, k slots 4..7
    f32x4 acc0 = {0.f, 0.f, 0.f, 0.f}, acc1 = acc0;

    STAGE(0); STAGE(1); STAGE(2);
#pragma unroll
    for (int t = 0; t < NSTEP; ++t) {
        if (NSTEP - t >= 3)      asm volatile("s_waitcnt vmcnt(6)" ::: "memory");
        else if (NSTEP - t == 2) asm volatile("s_waitcnt vmcnt(3)" ::: "memory");
        else                     asm volatile("s_waitcnt vmcnt(0)" ::: "memory");
        __builtin_amdgcn_s_barrier();
        __builtin_amdgcn_sched_barrier(0);
        if (t + 3 < NSTEP) STAGE(t + 3);
        const int b = t & 3;
        bf16x8 a0  = *(const bf16x8*)&As[b][wm + fr][e0];
        bf16x8 a1  = *(const bf16x8*)&As[b][wm + fr][e1];
        bf16x8 b00 = *(const bf16x8*)&Bs[b][wn + fr][e0];
        bf16x8 b01 = *(const bf16x8*)&Bs[b][wn + fr][e1];
        bf16x8 b10 = *(const bf16x8*)&Bs[b][wn + 16 + fr][e0];
        bf16x8 b11 = *(const bf16x8*)&Bs[b][wn + 16 + fr][e1];
        acc0 = __builtin_amdgcn_mfma_f32_16x16x32_bf16(a0, b00, acc0, 0, 0, 0);
        acc1 = __builtin_amdgcn_mfma_f32_16x16x32_bf16(a0, b10, acc1, 0, 0, 0);
        acc0 = __builtin_amdgcn_mfma_f32_16x16x32_bf16(a1, b01, acc0, 0, 0, 0);
        acc1 = __builtin_amdgcn_mfma_f32_16x16x32_bf16(a1, b11, acc1, 0, 0, 0);
    }
#undef STAGE

    const int orow = bm + wm + (fq << 2);
    const int ocol = bn + wn + fr;
    float bv0 = bias[ocol], bv1 = bias[ocol + 16];
#pragma unroll
    for (int r = 0; r < 4; ++r) {
        float v0 = acc0[r] + bv0;
        float v1 = acc1[r] + bv1;
        if (RELU) { v0 = fmaxf(v0, 0.f); v1 = fmaxf(v1, 0.f); }
        if (WF32) {
            C[(size_t)(orow + r) * N + ocol]      = v0;
            C[(size_t)(orow + r) * N + ocol + 16] = v1;
        }
        if (WBF16) {
            Cb[(size_t)(orow + r) * N + ocol]      = __float2bfloat16(v0);
            Cb[(size_t)(orow + r) * N + ocol + 16] = __float2bfloat16(v1);
        }
    }
}

// ---------------- weight transpose + bf16 convert ---------------------------
__global__ __launch_bounds__(256) void wconv_kernel(
    const float* __restrict__ W_pre, const float* __restrict__ Wq,
    const float* __restrict__ Wk, const float* __restrict__ Wv,
    const float* __restrict__ Wo, const float* __restrict__ W1,
    const float* __restrict__ W2, const float* __restrict__ W_post,
    __hip_bfloat16* wpre_t, __hip_bfloat16* wqkv_t, __hip_bfloat16* wo_t,
    __hip_bfloat16* w1_t, __hip_bfloat16* w2_t, __hip_bfloat16* wpost_t) {
    __shared__ float tile[64][65];
    int tb = blockIdx.x;
    const float* src; __hip_bfloat16* dst; int K, Kpad, kt, nt;
    if (tb < 32) {
        src = W_pre; dst = wpre_t; K = FIN; Kpad = FINPAD;
        kt = tb >> 3; nt = tb & 7;
    } else {
        int t2 = tb - 32; int mat = t2 >> 6; int tt = t2 & 63;
        kt = tt >> 3; nt = tt & 7; K = 512; Kpad = 512;
        if (mat == 36) { src = W_post; dst = wpost_t; }
        else {
            int l = mat / 6, j = mat % 6;
            const size_t WSZ = 262144;
            switch (j) {
                case 0: src = Wq + l * WSZ; dst = wqkv_t + l * 786432;          break;
                case 1: src = Wk + l * WSZ; dst = wqkv_t + l * 786432 + 262144; break;
                case 2: src = Wv + l * WSZ; dst = wqkv_t + l * 786432 + 524288; break;
                case 3: src = Wo + l * WSZ; dst = wo_t + l * WSZ;               break;
                case 4: src = W1 + l * WSZ; dst = w1_t + l * WSZ;               break;
                default: src = W2 + l * WSZ; dst = w2_t + l * WSZ;              break;
            }
        }
    }
    const int N = 512;
    int t = threadIdx.x;
    int k0 = kt * 64, n0 = nt * 64;
#pragma unroll
    for (int i = 0; i < 16; ++i) {
        int kk = (t >> 6) * 16 + i;
        int nn = t & 63;
        int k = k0 + kk;
        tile[kk][nn] = (k < K) ? src[(size_t)k * N + n0 + nn] : 0.f;
    }
    __syncthreads();
#pragma unroll
    for (int i = 0; i < 16; ++i) {
        int nn = (t >> 6) * 16 + i;
        int kk = t & 63;
        dst[(size_t)(n0 + nn) * Kpad + k0 + kk] = __float2bfloat16(tile[kk][nn]);
    }
}

__global__ void bias_concat_kernel(const float* __restrict__ bq,
                                   const float* __restrict__ bk,
                                   const float* __restrict__ bv,
                                   float* __restrict__ o) {
    int l = blockIdx.x, t = threadIdx.x;  // 512 threads
    o[l * QKVLD + t]        = bq[l * DMODEL + t];
    o[l * QKVLD + 512 + t]  = bk[l * DMODEL + t];
    o[l * QKVLD + 1024 + t] = bv[l * DMODEL + t];
}

// ---------------- attention phase A: per-chunk K^T V sums + K column sums --
__global__ __launch_bounds__(256) void attn_sums_kernel(
    const float* __restrict__ k, const float* __restrict__ v, int ld,
    float* __restrict__ kvsum, float* __restrict__ ksum) {
    __shared__ float Ks[CHUNK][33];
    __shared__ float Vs[CHUNK][33];
    int c = blockIdx.x, hh = blockIdx.y, b = blockIdx.z;
    int tid = threadIdx.x;
    size_t base = ((size_t)(b * SEQ + c * CHUNK)) * ld + hh * DHEAD;
#pragma unroll
    for (int i = 0; i < 8; ++i) {
        int s = (tid >> 5) + i * 8;
        int d = tid & 31;
        Ks[s][d] = phi(k[base + (size_t)s * ld + d]);
        Vs[s][d] = v[base + (size_t)s * ld + d];
    }
    __syncthreads();
    int m = tid & 31;
    float acc[4] = {0.f, 0.f, 0.f, 0.f};
    for (int s = 0; s < CHUNK; ++s) {
        float vm = Vs[s][m];
#pragma unroll
        for (int i = 0; i < 4; ++i)
            acc[i] = fmaf(Ks[s][(tid >> 5) + 8 * i], vm, acc[i]);
    }
    size_t ob = ((size_t)((b * NHEAD + hh) * NCHUNK + c)) * (DHEAD * DHEAD);
#pragma unroll
    for (int i = 0; i < 4; ++i)
        kvsum[ob + (size_t)((tid >> 5) + 8 * i) * DHEAD + m] = acc[i];
    if (tid < 32) {
        float s_ = 0.f;
        for (int s = 0; s < CHUNK; ++s) s_ += Ks[s][tid];
        ksum[((size_t)((b * NHEAD + hh) * NCHUNK + c)) * DHEAD + tid] = s_;
    }
}

// ---------------- attention phase B: exclusive scan over chunks ------------
__global__ __launch_bounds__(1024) void attn_scan_kernel(
    const float* __restrict__ kvsum, const float* __restrict__ ksum,
    float* __restrict__ state, float* __restrict__ kstate) {
    int bh = blockIdx.x;
    int tid = threadIdx.x;
    size_t base = (size_t)bh * NCHUNK * (DHEAD * DHEAD);
    float vals[NCHUNK];
#pragma unroll
    for (int c = 0; c < NCHUNK; ++c)
        vals[c] = kvsum[base + (size_t)c * (DHEAD * DHEAD) + tid];
    float run = 0.f;
#pragma unroll
    for (int c = 0; c < NCHUNK; ++c) {
        float nv = vals[c];
        vals[c] = run;
        run += nv;
    }
#pragma unroll
    for (int c = 0; c < NCHUNK; ++c)
        state[base + (size_t)c * (DHEAD * DHEAD) + tid] = vals[c];
    if (tid < 32) {
        size_t kb = (size_t)bh * NCHUNK * DHEAD;
        float kv[NCHUNK];
#pragma unroll
        for (int c = 0; c < NCHUNK; ++c) kv[c] = ksum[kb + c * DHEAD + tid];
        float rk = 0.f;
#pragma unroll
        for (int c = 0; c < NCHUNK; ++c) {
            float nv = kv[c];
            kstate[kb + c * DHEAD + tid] = rk;
            rk += nv;
        }
    }
}

// ---------------- attention phase C: intra-chunk + state application -------
__global__ __launch_bounds__(256) void attn_out_kernel(
    const float* __restrict__ q, const float* __restrict__ k,
    const float* __restrict__ v, int ld,
    const float* __restrict__ state, const float* __restrict__ kstate,
    __hip_bfloat16* __restrict__ out) {
    __shared__ float Qs[CHUNK][33];
    __shared__ float Ks[CHUNK][33];
    __shared__ float Vs[CHUNK][33];
    __shared__ float St[DHEAD][DHEAD];
    __shared__ float Aw[CHUNK][65];
    __shared__ float den[CHUNK];
    __shared__ float ksml[DHEAD];
    int c = blockIdx.x, hh = blockIdx.y, b = blockIdx.z;
    int tid = threadIdx.x;
    size_t base = ((size_t)(b * SEQ + c * CHUNK)) * ld + hh * DHEAD;
#pragma unroll
    for (int i = 0; i < 8; ++i) {
        int s = (tid >> 5) + i * 8;
        int d = tid & 31;
        Qs[s][d] = phi(q[base + (size_t)s * ld + d]);
        Ks[s][d] = phi(k[base + (size_t)s * ld + d]);
        Vs[s][d] = v[base + (size_t)s * ld + d];
    }
    size_t sb = ((size_t)((b * NHEAD + hh) * NCHUNK + c)) * (DHEAD * DHEAD);
#pragma unroll
    for (int i = 0; i < 4; ++i) {
        int idx = tid + i * 256;
        ((float*)St)[idx] = state[sb + idx];
    }
    if (tid < 32)
        ksml[tid] = kstate[((size_t)((b * NHEAD + hh) * NCHUNK + c)) * DHEAD + tid];
    __syncthreads();
#pragma unroll
    for (int i = 0; i < 16; ++i) {
        int s_ = (tid >> 6) + 4 * i;
        int t_ = tid & 63;
        float a_ = 0.f;
        if (t_ <= s_) {
            for (int d = 0; d < DHEAD; ++d)
                a_ = fmaf(Qs[s_][d], Ks[t_][d], a_);
        }
        Aw[s_][t_] = a_;
    }
    __syncthreads();
    if (tid < CHUNK) {
        int s_ = tid;
        float d_ = 0.f;
        for (int d = 0; d < DHEAD; ++d) d_ = fmaf(Qs[s_][d], ksml[d], d_);
        for (int t_ = 0; t_ <= s_; ++t_) d_ += Aw[s_][t_];
        den[s_] = 1.f / (d_ + 1e-6f);
    }
    __syncthreads();
    int m = tid & 31;
    size_t obase = ((size_t)(b * SEQ + c * CHUNK)) * DMODEL + hh * DHEAD;
#pragma unroll
    for (int i = 0; i < 8; ++i) {
        int s_ = (tid >> 5) * 8 + i;
        float o = 0.f;
        for (int d = 0; d < DHEAD; ++d) o = fmaf(Qs[s_][d], St[d][m], o);
        for (int t_ = 0; t_ <= s_; ++t_) o = fmaf(Aw[s_][t_], Vs[t_][m], o);
        out[obase + (size_t)s_ * DMODEL + m] = __float2bfloat16(o * den[s_]);
    }
}

// ---------------------------------------------------------------------------
template<int R, int WF, int WB, int K>
static inline void gemm(const __hip_bfloat16* A, const __hip_bfloat16* Bt,
                        const float* bias, float* C, __hip_bfloat16* Cb,
                        int M, int N, hipStream_t s) {
    gemm_bf16_kernel<R, WF, WB, K><<<(M / 32) * (N / 64), 256, 0, s>>>(A, Bt, bias, C, Cb, N);
}

extern "C" void kernel_launch(void* const* d_in, const int* in_sizes, int n_in,
                              void* d_out, int out_size, void* d_ws, size_t ws_size,
                              hipStream_t stream) {
    const float* x      = (const float*)d_in[0];
    const float* g_in   = (const float*)d_in[1];
    const float* b_in   = (const float*)d_in[2];
    const float* W_pre  = (const float*)d_in[3];
    const float* b_pre  = (const float*)d_in[4];
    const float* Wq     = (const float*)d_in[5];
    const float* bq     = (const float*)d_in[6];
    const float* Wk     = (const float*)d_in[7];
    const float* bk     = (const float*)d_in[8];
    const float* Wv     = (const float*)d_in[9];
    const float* bv     = (const float*)d_in[10];
    const float* Wo     = (const float*)d_in[11];
    const float* bo     = (const float*)d_in[12];
    const float* W1     = (const float*)d_in[13];
    const float* bf1    = (const float*)d_in[14];
    const float* W2     = (const float*)d_in[15];
    const float* bf2    = (const float*)d_in[16];
    const float* ln1_g  = (const float*)d_in[17];
    const float* ln1_b  = (const float*)d_in[18];
    const float* ln2_g  = (const float*)d_in[19];
    const float* ln2_b  = (const float*)d_in[20];
    const float* lnf_g  = (const float*)d_in[21];
    const float* lnf_b  = (const float*)d_in[22];
    const float* W_post = (const float*)d_in[23];
    const float* b_post = (const float*)d_in[24];
    (void)in_sizes; (void)n_in; (void)out_size; (void)ws_size;

    float* ws = (float*)d_ws;
    const size_t SZ = (size_t)NROW * DMODEL;          // 1048576
    float* h       = ws;
    float* qkv     = h + SZ;                          // 2048*1536 = 3145728
    float* t1      = qkv + 3145728;
    float* kvsum   = t1 + SZ;                         // 524288
    float* stat    = kvsum + 524288;
    float* ksum    = stat + 524288;                   // 16384
    float* kstate  = ksum + 16384;
    float* qkvbias = kstate + 16384;                  // 6*1536 = 9216
    __hip_bfloat16* bp = (__hip_bfloat16*)(qkvbias + 9216);
    __hip_bfloat16* hb     = bp;            bp += SZ;
    __hip_bfloat16* xnb    = bp;            bp += (size_t)NROW * FINPAD;   // 524288
    __hip_bfloat16* attb   = bp;            bp += SZ;
    __hip_bfloat16* ffb    = bp;            bp += SZ;
    __hip_bfloat16* t0b    = bp;            bp += SZ;
    __hip_bfloat16* wpre_t = bp;            bp += (size_t)DMODEL * FINPAD; // 131072
    __hip_bfloat16* wqkv_t = bp;            bp += (size_t)NLAYER * 786432;
    __hip_bfloat16* wo_t   = bp;            bp += (size_t)NLAYER * 262144;
    __hip_bfloat16* w1_t   = bp;            bp += (size_t)NLAYER * 262144;
    __hip_bfloat16* w2_t   = bp;            bp += (size_t)NLAYER * 262144;
    __hip_bfloat16* wpost_t= bp;

    // one-time-per-call weight conversion (graph-safe, deterministic)
    wconv_kernel<<<32 + 37 * 64, 256, 0, stream>>>(
        W_pre, Wq, Wk, Wv, Wo, W1, W2, W_post,
        wpre_t, wqkv_t, wo_t, w1_t, w2_t, wpost_t);
    bias_concat_kernel<<<NLAYER, 512, 0, stream>>>(bq, bk, bv, qkvbias);

    // input LN (bf16, K padded 240->256) + pre projection (h fp32 + hb bf16)
    ln_kernel<<<NROW, 256, 0, stream>>>(x, nullptr, g_in, b_in, nullptr, xnb, FIN, FINPAD);
    gemm<0, 1, 1, FINPAD>(xnb, wpre_t, b_pre, h, hb, NROW, DMODEL, stream);

    dim3 ag(NCHUNK, NHEAD, 2);
    for (int l = 0; l < NLAYER; ++l) {
        // fused QKV projection -> qkv fp32 [2048][1536]
        gemm<0, 1, 0, DMODEL>(hb, wqkv_t + (size_t)l * 786432, qkvbias + l * QKVLD,
                              qkv, nullptr, NROW, QKVLD, stream);
        const float* qp = qkv;
        const float* kp = qkv + 512;
        const float* vp = qkv + 1024;
        attn_sums_kernel<<<ag, 256, 0, stream>>>(kp, vp, QKVLD, kvsum, ksum);
        attn_scan_kernel<<<32, 1024, 0, stream>>>(kvsum, ksum, stat, kstate);
        attn_out_kernel<<<ag, 256, 0, stream>>>(qp, kp, vp, QKVLD, stat, kstate, attb);
        gemm<0, 1, 0, DMODEL>(attb, wo_t + (size_t)l * 262144, bo + l * DMODEL,
                              t1, nullptr, NROW, DMODEL, stream);
        ln_kernel<<<NROW, 256, 0, stream>>>(h, t1, ln1_g + l * DMODEL, ln1_b + l * DMODEL,
                                            h, hb, DMODEL, DMODEL);
        gemm<1, 0, 1, DMODEL>(hb, w1_t + (size_t)l * 262144, bf1 + l * DMODEL,
                              nullptr, ffb, NROW, DMODEL, stream);
        gemm<0, 1, 0, DMODEL>(ffb, w2_t + (size_t)l * 262144, bf2 + l * DMODEL,
                              t1, nullptr, NROW, DMODEL, stream);
        ln_kernel<<<NROW, 256, 0, stream>>>(h, t1, ln2_g + l * DMODEL, ln2_b + l * DMODEL,
                                            h, hb, DMODEL, DMODEL);
    }

    // final LN (bf16 only) + post projection (fp32 to d_out)
    ln_kernel<<<NROW, 256, 0, stream>>>(h, nullptr, lnf_g, lnf_b, nullptr, t0b, DMODEL, DMODEL);
    gemm<0, 1, 0, DMODEL>(t0b, wpost_t, b_post, (float*)d_out, nullptr, NROW, DMODEL, stream);
}

// Round 6
// 368.036 us; speedup vs baseline: 1.6989x; 1.2741x over previous
//
#include <hip/hip_runtime.h>
#include <hip/hip_bf16.h>
#include <cmath>

#define NROW 2048      // B*S
#define DMODEL 512
#define FIN 240
#define FINPAD 256
#define NHEAD 16
#define DHEAD 32
#define CHUNK 64
#define NCHUNK 16      // S / CHUNK
#define NLAYER 6
#define SEQ 1024
#define QKVLD 1536

typedef __attribute__((ext_vector_type(8))) short bf16x8;
typedef __attribute__((ext_vector_type(4))) float f32x4;

#define MFMA_BF16 __builtin_amdgcn_mfma_f32_16x16x32_bf16

// phi(x) = elu(x) + 1
__device__ __forceinline__ float phi(float x) {
    return x > 0.f ? x + 1.f : expf(x);
}

__device__ __forceinline__ void load_lds16(const void* g, void* l) {
    __builtin_amdgcn_global_load_lds(
        (const __attribute__((address_space(1))) void*)g,
        (__attribute__((address_space(3))) void*)l, 16, 0, 0);
}

// ---------------- LayerNorm (optional residual add, fp32 and/or bf16 out) --
__global__ __launch_bounds__(256) void ln_kernel(
    const float* __restrict__ in, const float* __restrict__ res,
    const float* __restrict__ g, const float* __restrict__ b,
    float* __restrict__ out, __hip_bfloat16* __restrict__ outb,
    int C, int Cpad) {
    int row = blockIdx.x;
    int tid = threadIdx.x;
    const float* xr = in + (size_t)row * C;
    const float* rr = res ? res + (size_t)row * C : nullptr;
    float vals[2];
    float sum = 0.f, sq = 0.f;
#pragma unroll
    for (int i = 0; i < 2; ++i) {
        int c = tid + i * 256;
        float v = 0.f;
        if (c < C) { v = xr[c]; if (rr) v += rr[c]; }
        vals[i] = v;
        sum += v; sq += v * v;
    }
#pragma unroll
    for (int off = 32; off > 0; off >>= 1) {
        sum += __shfl_xor(sum, off, 64);
        sq  += __shfl_xor(sq,  off, 64);
    }
    __shared__ float red[8];
    int wv = tid >> 6, ln = tid & 63;
    if (ln == 0) { red[wv] = sum; red[4 + wv] = sq; }
    __syncthreads();
    sum = red[0] + red[1] + red[2] + red[3];
    sq  = red[4] + red[5] + red[6] + red[7];
    float mean = sum / (float)C;
    float var  = sq / (float)C - mean * mean;
    float rstd = rsqrtf(var + 1e-5f);
#pragma unroll
    for (int i = 0; i < 2; ++i) {
        int c = tid + i * 256;
        float y = (vals[i] - mean) * rstd;
        if (c < C) {
            y = y * g[c] + b[c];
            if (out) out[(size_t)row * C + c] = y;
        }
        if (outb && c < Cpad)
            outb[(size_t)row * Cpad + c] = __float2bfloat16(c < C ? y : 0.f);
    }
}

// ---------------- bf16 MFMA GEMM, counted-vmcnt ring pipeline ---------------
// C = A[M,K] * Bt[N,K]^T + bias. BM=32, BN=64, BK=64, ring-4 LDS buffers,
// pre-swizzled global_load_lds staging, counted vmcnt (never 0 mid-loop).
// PHI: apply phi() to output cols < 1024 (fused QKV feature map).
template<int RELU, int WF32, int WBF16, int PHI, int K>
__global__ __launch_bounds__(256) void gemm_bf16_kernel(
    const __hip_bfloat16* __restrict__ A, const __hip_bfloat16* __restrict__ Bt,
    const float* __restrict__ bias,
    float* __restrict__ C, __hip_bfloat16* __restrict__ Cb,
    int N) {
    constexpr int NSTEP = K / 64;
    __shared__ __align__(16) __hip_bfloat16 As[4][32][64];
    __shared__ __align__(16) __hip_bfloat16 Bs[4][64][64];
    const int tid = threadIdx.x, lane = tid & 63, w = tid >> 6;
    const int nN = N >> 6;
    const int bm = (blockIdx.x / nN) * 32;
    const int bn = (blockIdx.x % nN) * 64;

    const int srow  = lane >> 3;                 // 0..7
    const int sslot = (lane & 7) ^ srow;         // pre-swizzled global slot
    const size_t aoff = (size_t)srow * K + (size_t)sslot * 8;
    const __hip_bfloat16* gA  = A  + (size_t)(bm + w * 8) * K + aoff;
    const __hip_bfloat16* gB0 = Bt + (size_t)(bn + w * 8) * K + aoff;
    const __hip_bfloat16* gB1 = Bt + (size_t)(bn + 32 + w * 8) * K + aoff;

#define STAGE(t) do { \
        load_lds16(gA  + (size_t)(t) * 64, &As[(t) & 3][w * 8][0]); \
        load_lds16(gB0 + (size_t)(t) * 64, &Bs[(t) & 3][w * 8][0]); \
        load_lds16(gB1 + (size_t)(t) * 64, &Bs[(t) & 3][32 + w * 8][0]); \
    } while (0)

    const int wm = (w >> 1) << 4, wn = (w & 1) << 5;
    const int fr = lane & 15, fq = lane >> 4;
    const int sw = fr & 7;
    const int e0 = ((fq      ^ sw) << 3);
    const int e1 = (((fq | 4) ^ sw) << 3);
    f32x4 acc0 = {0.f, 0.f, 0.f, 0.f}, acc1 = acc0;

    STAGE(0); STAGE(1); STAGE(2);
#pragma unroll
    for (int t = 0; t < NSTEP; ++t) {
        if (NSTEP - t >= 3)      asm volatile("s_waitcnt vmcnt(6)" ::: "memory");
        else if (NSTEP - t == 2) asm volatile("s_waitcnt vmcnt(3)" ::: "memory");
        else                     asm volatile("s_waitcnt vmcnt(0)" ::: "memory");
        __builtin_amdgcn_s_barrier();
        __builtin_amdgcn_sched_barrier(0);
        if (t + 3 < NSTEP) STAGE(t + 3);
        const int b = t & 3;
        bf16x8 a0  = *(const bf16x8*)&As[b][wm + fr][e0];
        bf16x8 a1  = *(const bf16x8*)&As[b][wm + fr][e1];
        bf16x8 b00 = *(const bf16x8*)&Bs[b][wn + fr][e0];
        bf16x8 b01 = *(const bf16x8*)&Bs[b][wn + fr][e1];
        bf16x8 b10 = *(const bf16x8*)&Bs[b][wn + 16 + fr][e0];
        bf16x8 b11 = *(const bf16x8*)&Bs[b][wn + 16 + fr][e1];
        acc0 = MFMA_BF16(a0, b00, acc0, 0, 0, 0);
        acc1 = MFMA_BF16(a0, b10, acc1, 0, 0, 0);
        acc0 = MFMA_BF16(a1, b01, acc0, 0, 0, 0);
        acc1 = MFMA_BF16(a1, b11, acc1, 0, 0, 0);
    }
#undef STAGE

    const int orow = bm + wm + (fq << 2);
    const int ocol = bn + wn + fr;
    float bv0 = bias[ocol], bv1 = bias[ocol + 16];
#pragma unroll
    for (int r = 0; r < 4; ++r) {
        float v0 = acc0[r] + bv0;
        float v1 = acc1[r] + bv1;
        if (RELU) { v0 = fmaxf(v0, 0.f); v1 = fmaxf(v1, 0.f); }
        if (PHI) {
            if (ocol < 1024)      v0 = phi(v0);
            if (ocol + 16 < 1024) v1 = phi(v1);
        }
        if (WF32) {
            C[(size_t)(orow + r) * N + ocol]      = v0;
            C[(size_t)(orow + r) * N + ocol + 16] = v1;
        }
        if (WBF16) {
            Cb[(size_t)(orow + r) * N + ocol]      = __float2bfloat16(v0);
            Cb[(size_t)(orow + r) * N + ocol + 16] = __float2bfloat16(v1);
        }
    }
}

// ---------------- weight transpose + bf16 convert (+ qkv bias concat) -------
__global__ __launch_bounds__(256) void wconv_kernel(
    const float* __restrict__ W_pre, const float* __restrict__ Wq,
    const float* __restrict__ Wk, const float* __restrict__ Wv,
    const float* __restrict__ Wo, const float* __restrict__ W1,
    const float* __restrict__ W2, const float* __restrict__ W_post,
    const float* __restrict__ bq, const float* __restrict__ bk,
    const float* __restrict__ bv, float* __restrict__ qkvbias,
    __hip_bfloat16* wpre_t, __hip_bfloat16* wqkv_t, __hip_bfloat16* wo_t,
    __hip_bfloat16* w1_t, __hip_bfloat16* w2_t, __hip_bfloat16* wpost_t) {
    __shared__ float tile[64][65];
    int tb = blockIdx.x;
    if (tb >= 2400) {               // qkv bias concat: 6 blocks
        int l = tb - 2400;
        for (int i = threadIdx.x; i < 512; i += 256) {
            qkvbias[l * QKVLD + i]        = bq[l * DMODEL + i];
            qkvbias[l * QKVLD + 512 + i]  = bk[l * DMODEL + i];
            qkvbias[l * QKVLD + 1024 + i] = bv[l * DMODEL + i];
        }
        return;
    }
    const float* src; __hip_bfloat16* dst; int K, Kpad, kt, nt;
    if (tb < 32) {
        src = W_pre; dst = wpre_t; K = FIN; Kpad = FINPAD;
        kt = tb >> 3; nt = tb & 7;
    } else {
        int t2 = tb - 32; int mat = t2 >> 6; int tt = t2 & 63;
        kt = tt >> 3; nt = tt & 7; K = 512; Kpad = 512;
        if (mat == 36) { src = W_post; dst = wpost_t; }
        else {
            int l = mat / 6, j = mat % 6;
            const size_t WSZ = 262144;
            switch (j) {
                case 0: src = Wq + l * WSZ; dst = wqkv_t + l * 786432;          break;
                case 1: src = Wk + l * WSZ; dst = wqkv_t + l * 786432 + 262144; break;
                case 2: src = Wv + l * WSZ; dst = wqkv_t + l * 786432 + 524288; break;
                case 3: src = Wo + l * WSZ; dst = wo_t + l * WSZ;               break;
                case 4: src = W1 + l * WSZ; dst = w1_t + l * WSZ;               break;
                default: src = W2 + l * WSZ; dst = w2_t + l * WSZ;              break;
            }
        }
    }
    const int N = 512;
    int t = threadIdx.x;
    int k0 = kt * 64, n0 = nt * 64;
#pragma unroll
    for (int i = 0; i < 16; ++i) {
        int kk = (t >> 6) * 16 + i;
        int nn = t & 63;
        int k = k0 + kk;
        tile[kk][nn] = (k < K) ? src[(size_t)k * N + n0 + nn] : 0.f;
    }
    __syncthreads();
#pragma unroll
    for (int i = 0; i < 16; ++i) {
        int nn = (t >> 6) * 16 + i;
        int kk = t & 63;
        dst[(size_t)(n0 + nn) * Kpad + k0 + kk] = __float2bfloat16(tile[kk][nn]);
    }
}

// ---------------- attention phase A: S_c = V^T K (32x32) + K col sums ------
// grid (NCHUNK, NHEAD, B), 64 threads. qkvb: bf16 [2048][1536], Q|phi'd, K|phi'd, V.
__global__ __launch_bounds__(64) void attn_state_kernel(
    const __hip_bfloat16* __restrict__ qkvb,
    float* __restrict__ Sg, float* __restrict__ ksumg) {
    __shared__ __hip_bfloat16 Kt[32][72];
    __shared__ __hip_bfloat16 Vt[32][72];
    int c = blockIdx.x, hh = blockIdx.y, b = blockIdx.z;
    int t = threadIdx.x;
    int sub = t >> 2, slot = t & 3;
    size_t rb = ((size_t)(b * SEQ + c * CHUNK)) * QKVLD + hh * DHEAD;
#pragma unroll
    for (int it = 0; it < 4; ++it) {
        int s = it * 16 + sub;
        bf16x8 kv = *(const bf16x8*)&qkvb[rb + (size_t)s * QKVLD + 512 + slot * 8];
        bf16x8 vv = *(const bf16x8*)&qkvb[rb + (size_t)s * QKVLD + 1024 + slot * 8];
#pragma unroll
        for (int i = 0; i < 8; ++i) {
            Kt[slot * 8 + i][s] = ((const __hip_bfloat16*)&kv)[i];
            Vt[slot * 8 + i][s] = ((const __hip_bfloat16*)&vv)[i];
        }
    }
    __syncthreads();
    int fr = t & 15, fq = t >> 4;
    f32x4 a00 = {0.f,0.f,0.f,0.f}, a01 = a00, a10 = a00, a11 = a00;
#pragma unroll
    for (int ks = 0; ks < 2; ++ks) {
        bf16x8 v0 = *(const bf16x8*)&Vt[fr][ks * 32 + fq * 8];
        bf16x8 v1 = *(const bf16x8*)&Vt[16 + fr][ks * 32 + fq * 8];
        bf16x8 k0 = *(const bf16x8*)&Kt[fr][ks * 32 + fq * 8];
        bf16x8 k1 = *(const bf16x8*)&Kt[16 + fr][ks * 32 + fq * 8];
        a00 = MFMA_BF16(v0, k0, a00, 0, 0, 0);
        a01 = MFMA_BF16(v0, k1, a01, 0, 0, 0);
        a10 = MFMA_BF16(v1, k0, a10, 0, 0, 0);
        a11 = MFMA_BF16(v1, k1, a11, 0, 0, 0);
    }
    size_t ob = ((size_t)((b * NHEAD + hh) * NCHUNK + c)) * 1024;
#pragma unroll
    for (int r = 0; r < 4; ++r) {
        int m0 = fq * 4 + r;
        Sg[ob + (size_t)m0 * 32 + fr]             = a00[r];
        Sg[ob + (size_t)m0 * 32 + 16 + fr]        = a01[r];
        Sg[ob + (size_t)(16 + m0) * 32 + fr]      = a10[r];
        Sg[ob + (size_t)(16 + m0) * 32 + 16 + fr] = a11[r];
    }
    if (t < 32) {
        float s_ = 0.f;
        for (int s = 0; s < CHUNK; ++s) s_ += __bfloat162float(Kt[t][s]);
        ksumg[((size_t)((b * NHEAD + hh) * NCHUNK + c)) * 32 + t] = s_;
    }
}

// ---------------- attention phase B: intra-chunk (MFMA) + state + output ---
// grid (NCHUNK, NHEAD, B), 256 threads (4 waves; wave w owns rows w*16..+15).
__global__ __launch_bounds__(256) void attn_out_kernel(
    const __hip_bfloat16* __restrict__ qkvb,
    const float* __restrict__ Sg, const float* __restrict__ ksumg,
    __hip_bfloat16* __restrict__ out) {
    __shared__ __hip_bfloat16 Qs[64][40];
    __shared__ __hip_bfloat16 Ks[64][40];
    __shared__ __hip_bfloat16 Vt[32][72];
    __shared__ __hip_bfloat16 Awb[64][72];
    __shared__ __hip_bfloat16 Stb[32][40];
    __shared__ float den[64];
    __shared__ float ksml[32];
    int c = blockIdx.x, hh = blockIdx.y, b = blockIdx.z;
    int tid = threadIdx.x, lane = tid & 63, w = tid >> 6;
    size_t rb = ((size_t)(b * SEQ + c * CHUNK)) * QKVLD + hh * DHEAD;
    {
        int row = tid >> 2, slot = tid & 3;
        *(bf16x8*)&Qs[row][slot * 8] =
            *(const bf16x8*)&qkvb[rb + (size_t)row * QKVLD + slot * 8];
        *(bf16x8*)&Ks[row][slot * 8] =
            *(const bf16x8*)&qkvb[rb + (size_t)row * QKVLD + 512 + slot * 8];
        bf16x8 vv = *(const bf16x8*)&qkvb[rb + (size_t)row * QKVLD + 1024 + slot * 8];
        if (row < 64) {
#pragma unroll
            for (int i = 0; i < 8; ++i)
                Vt[slot * 8 + i][row] = ((const __hip_bfloat16*)&vv)[i];
        }
    }
    // state prefix (sum of prior chunks' S), converted to bf16
    size_t sb = ((size_t)((b * NHEAD + hh) * NCHUNK)) * 1024;
    {
        f32x4 st = {0.f, 0.f, 0.f, 0.f};
        for (int cp = 0; cp < c; ++cp)
            st += *(const f32x4*)&Sg[sb + (size_t)cp * 1024 + tid * 4];
        int m = tid >> 3, d0 = (tid & 7) * 4;
#pragma unroll
        for (int i = 0; i < 4; ++i) Stb[m][d0 + i] = __float2bfloat16(st[i]);
    }
    if (tid < 32) {
        size_t kb = ((size_t)((b * NHEAD + hh) * NCHUNK)) * 32;
        float s_ = 0.f;
        for (int cp = 0; cp < c; ++cp) s_ += ksumg[kb + cp * 32 + tid];
        ksml[tid] = s_;
    }
    __syncthreads();
    int fr = lane & 15, fq = lane >> 4;
    bf16x8 aQ = *(const bf16x8*)&Qs[w * 16 + fr][fq * 8];
    f32x4 p[4];
#pragma unroll
    for (int j = 0; j < 4; ++j) {
        f32x4 z = {0.f, 0.f, 0.f, 0.f};
        bf16x8 bK = *(const bf16x8*)&Ks[j * 16 + fr][fq * 8];
        p[j] = MFMA_BF16(aQ, bK, z, 0, 0, 0);
    }
    // causal mask + row sums (denominator, fp32)
    float rs[4] = {0.f, 0.f, 0.f, 0.f};
#pragma unroll
    for (int j = 0; j < 4; ++j) {
        int tcol = j * 16 + fr;
#pragma unroll
        for (int r = 0; r < 4; ++r) {
            int s = w * 16 + fq * 4 + r;
            float val = (tcol <= s) ? p[j][r] : 0.f;
            p[j][r] = val;
            rs[r] += val;
        }
    }
#pragma unroll
    for (int off = 8; off > 0; off >>= 1) {
#pragma unroll
        for (int r = 0; r < 4; ++r) rs[r] += __shfl_xor(rs[r], off, 64);
    }
    if (fr == 0) {
#pragma unroll
        for (int r = 0; r < 4; ++r) den[w * 16 + fq * 4 + r] = rs[r];
    }
    // masked scores -> bf16 LDS (wave-local rows)
#pragma unroll
    for (int j = 0; j < 4; ++j)
#pragma unroll
        for (int r = 0; r < 4; ++r)
            Awb[w * 16 + fq * 4 + r][j * 16 + fr] = __float2bfloat16(p[j][r]);
    __syncthreads();
    if (tid < 64) {
        float dq = den[tid];
        float dst_ = 0.f;
#pragma unroll
        for (int d = 0; d < 32; ++d)
            dst_ += __bfloat162float(Qs[tid][d]) * ksml[d];
        den[tid] = 1.f / (dq + dst_ + 1e-6f);
    }
    __syncthreads();
    size_t orb = ((size_t)(b * SEQ + c * CHUNK)) * DMODEL + hh * DHEAD;
#pragma unroll
    for (int mf = 0; mf < 2; ++mf) {
        f32x4 acc = {0.f, 0.f, 0.f, 0.f};
        bf16x8 bS = *(const bf16x8*)&Stb[mf * 16 + fr][fq * 8];
        acc = MFMA_BF16(aQ, bS, acc, 0, 0, 0);
#pragma unroll
        for (int ks = 0; ks < 2; ++ks) {
            bf16x8 aA = *(const bf16x8*)&Awb[w * 16 + fr][ks * 32 + fq * 8];
            bf16x8 bV = *(const bf16x8*)&Vt[mf * 16 + fr][ks * 32 + fq * 8];
            acc = MFMA_BF16(aA, bV, acc, 0, 0, 0);
        }
#pragma unroll
        for (int r = 0; r < 4; ++r) {
            int s = w * 16 + fq * 4 + r;
            out[orb + (size_t)s * DMODEL + mf * 16 + fr] =
                __float2bfloat16(acc[r] * den[s]);
        }
    }
}

// ---------------------------------------------------------------------------
template<int R, int WF, int WB, int PHI, int K>
static inline void gemm(const __hip_bfloat16* A, const __hip_bfloat16* Bt,
                        const float* bias, float* C, __hip_bfloat16* Cb,
                        int M, int N, hipStream_t s) {
    gemm_bf16_kernel<R, WF, WB, PHI, K><<<(M / 32) * (N / 64), 256, 0, s>>>(A, Bt, bias, C, Cb, N);
}

extern "C" void kernel_launch(void* const* d_in, const int* in_sizes, int n_in,
                              void* d_out, int out_size, void* d_ws, size_t ws_size,
                              hipStream_t stream) {
    const float* x      = (const float*)d_in[0];
    const float* g_in   = (const float*)d_in[1];
    const float* b_in   = (const float*)d_in[2];
    const float* W_pre  = (const float*)d_in[3];
    const float* b_pre  = (const float*)d_in[4];
    const float* Wq     = (const float*)d_in[5];
    const float* bq     = (const float*)d_in[6];
    const float* Wk     = (const float*)d_in[7];
    const float* bk     = (const float*)d_in[8];
    const float* Wv     = (const float*)d_in[9];
    const float* bv     = (const float*)d_in[10];
    const float* Wo     = (const float*)d_in[11];
    const float* bo     = (const float*)d_in[12];
    const float* W1     = (const float*)d_in[13];
    const float* bf1    = (const float*)d_in[14];
    const float* W2     = (const float*)d_in[15];
    const float* bf2    = (const float*)d_in[16];
    const float* ln1_g  = (const float*)d_in[17];
    const float* ln1_b  = (const float*)d_in[18];
    const float* ln2_g  = (const float*)d_in[19];
    const float* ln2_b  = (const float*)d_in[20];
    const float* lnf_g  = (const float*)d_in[21];
    const float* lnf_b  = (const float*)d_in[22];
    const float* W_post = (const float*)d_in[23];
    const float* b_post = (const float*)d_in[24];
    (void)in_sizes; (void)n_in; (void)out_size; (void)ws_size;

    float* ws = (float*)d_ws;
    const size_t SZ = (size_t)NROW * DMODEL;          // 1048576
    float* h       = ws;
    float* t1      = h + SZ;
    float* Sg      = t1 + SZ;                         // 512*1024 = 524288
    float* ksumg   = Sg + 524288;                     // 16384
    float* qkvbias = ksumg + 16384;                   // 9216
    __hip_bfloat16* bp = (__hip_bfloat16*)(qkvbias + 9216);
    __hip_bfloat16* hb     = bp;            bp += SZ;
    __hip_bfloat16* qkvb   = bp;            bp += (size_t)NROW * QKVLD;    // 3145728
    __hip_bfloat16* xnb    = bp;            bp += (size_t)NROW * FINPAD;   // 524288
    __hip_bfloat16* attb   = bp;            bp += SZ;
    __hip_bfloat16* ffb    = bp;            bp += SZ;
    __hip_bfloat16* t0b    = bp;            bp += SZ;
    __hip_bfloat16* wpre_t = bp;            bp += (size_t)DMODEL * FINPAD; // 131072
    __hip_bfloat16* wqkv_t = bp;            bp += (size_t)NLAYER * 786432;
    __hip_bfloat16* wo_t   = bp;            bp += (size_t)NLAYER * 262144;
    __hip_bfloat16* w1_t   = bp;            bp += (size_t)NLAYER * 262144;
    __hip_bfloat16* w2_t   = bp;            bp += (size_t)NLAYER * 262144;
    __hip_bfloat16* wpost_t= bp;

    // one-time-per-call weight conversion + qkv bias concat
    wconv_kernel<<<2406, 256, 0, stream>>>(
        W_pre, Wq, Wk, Wv, Wo, W1, W2, W_post,
        bq, bk, bv, qkvbias,
        wpre_t, wqkv_t, wo_t, w1_t, w2_t, wpost_t);

    // input LN (bf16, K padded 240->256) + pre projection (h fp32 + hb bf16)
    ln_kernel<<<NROW, 256, 0, stream>>>(x, nullptr, g_in, b_in, nullptr, xnb, FIN, FINPAD);
    gemm<0, 1, 1, 0, FINPAD>(xnb, wpre_t, b_pre, h, hb, NROW, DMODEL, stream);

    dim3 ag(NCHUNK, NHEAD, 2);
    for (int l = 0; l < NLAYER; ++l) {
        // fused QKV projection -> bf16 [2048][1536], phi applied to Q,K cols
        gemm<0, 0, 1, 1, DMODEL>(hb, wqkv_t + (size_t)l * 786432, qkvbias + l * QKVLD,
                                 nullptr, qkvb, NROW, QKVLD, stream);
        attn_state_kernel<<<ag, 64, 0, stream>>>(qkvb, Sg, ksumg);
        attn_out_kernel<<<ag, 256, 0, stream>>>(qkvb, Sg, ksumg, attb);
        gemm<0, 1, 0, 0, DMODEL>(attb, wo_t + (size_t)l * 262144, bo + l * DMODEL,
                                 t1, nullptr, NROW, DMODEL, stream);
        ln_kernel<<<NROW, 256, 0, stream>>>(h, t1, ln1_g + l * DMODEL, ln1_b + l * DMODEL,
                                            h, hb, DMODEL, DMODEL);
        gemm<1, 0, 1, 0, DMODEL>(hb, w1_t + (size_t)l * 262144, bf1 + l * DMODEL,
                                 nullptr, ffb, NROW, DMODEL, stream);
        gemm<0, 1, 0, 0, DMODEL>(ffb, w2_t + (size_t)l * 262144, bf2 + l * DMODEL,
                                 t1, nullptr, NROW, DMODEL, stream);
        ln_kernel<<<NROW, 256, 0, stream>>>(h, t1, ln2_g + l * DMODEL, ln2_b + l * DMODEL,
                                            h, hb, DMODEL, DMODEL);
    }

    // final LN (bf16 only) + post projection (fp32 to d_out)
    ln_kernel<<<NROW, 256, 0, stream>>>(h, nullptr, lnf_g, lnf_b, nullptr, t0b, DMODEL, DMODEL);
    gemm<0, 1, 0, 0, DMODEL>(t0b, wpost_t, b_post, (float*)d_out, nullptr, NROW, DMODEL, stream);
}

// Round 8
// 348.398 us; speedup vs baseline: 1.7946x; 1.0564x over previous
//
#include <hip/hip_runtime.h>
#include <hip/hip_bf16.h>
#include <cmath>

#define NROW 2048      // B*S
#define DMODEL 512
#define FIN 240
#define FINPAD 256
#define NHEAD 16
#define DHEAD 32
#define CHUNK 64
#define NCHUNK 16      // S / CHUNK
#define NLAYER 6
#define SEQ 1024
#define QKVLD 1536

typedef __attribute__((ext_vector_type(8))) short bf16x8;
typedef __attribute__((ext_vector_type(4))) float f32x4;
typedef __attribute__((ext_vector_type(4))) unsigned short u16x4;

#define MFMA_BF16 __builtin_amdgcn_mfma_f32_16x16x32_bf16

// phi(x) = elu(x) + 1
__device__ __forceinline__ float phi(float x) {
    return x > 0.f ? x + 1.f : expf(x);
}

__device__ __forceinline__ float bf2f(unsigned short u) {
    return __uint_as_float((unsigned)u << 16);
}

__device__ __forceinline__ unsigned short f2bf_bits(float z) {
    __hip_bfloat16 hb_ = __float2bfloat16(z);
    return *reinterpret_cast<unsigned short*>(&hb_);
}

__device__ __forceinline__ void load_lds16(const void* g, void* l) {
    __builtin_amdgcn_global_load_lds(
        (const __attribute__((address_space(1))) void*)g,
        (__attribute__((address_space(3))) void*)l, 16, 0, 0);
}

// ---------------- LayerNorm, 1 wave/row, float4 loads, shfl-only reduce ----
// C <= 512 (multiple of 4), Cpad <= 512
__global__ __launch_bounds__(64) void ln_kernel(
    const float* __restrict__ in, const float* __restrict__ res,
    const float* __restrict__ g, const float* __restrict__ b,
    float* __restrict__ out, __hip_bfloat16* __restrict__ outb,
    int C, int Cpad) {
    int row = blockIdx.x;
    int t = threadIdx.x;
    const float* xr = in + (size_t)row * C;
    const float* rr = res ? res + (size_t)row * C : nullptr;
    f32x4 v[2] = {{0.f,0.f,0.f,0.f},{0.f,0.f,0.f,0.f}};
    float sum = 0.f, sq = 0.f;
#pragma unroll
    for (int i = 0; i < 2; ++i) {
        int c = (t + i * 64) * 4;
        if (c < C) {
            f32x4 x_ = *(const f32x4*)&xr[c];
            if (rr) x_ += *(const f32x4*)&rr[c];
            v[i] = x_;
#pragma unroll
            for (int j = 0; j < 4; ++j) { sum += x_[j]; sq += x_[j] * x_[j]; }
        }
    }
#pragma unroll
    for (int off = 32; off > 0; off >>= 1) {
        sum += __shfl_xor(sum, off, 64);
        sq  += __shfl_xor(sq,  off, 64);
    }
    float mean = sum / (float)C;
    float var  = sq / (float)C - mean * mean;
    float rstd = rsqrtf(var + 1e-5f);
#pragma unroll
    for (int i = 0; i < 2; ++i) {
        int c = (t + i * 64) * 4;
        f32x4 y;
#pragma unroll
        for (int j = 0; j < 4; ++j) y[j] = (v[i][j] - mean) * rstd;
        if (c < C) {
            f32x4 gg = *(const f32x4*)&g[c];
            f32x4 bb = *(const f32x4*)&b[c];
#pragma unroll
            for (int j = 0; j < 4; ++j) y[j] = y[j] * gg[j] + bb[j];
            if (out) *(f32x4*)&out[(size_t)row * C + c] = y;
        }
        if (outb && c < Cpad) {
            u16x4 o;
#pragma unroll
            for (int j = 0; j < 4; ++j) {
                float z = (c + j < C) ? y[j] : 0.f;
                o[j] = f2bf_bits(z);
            }
            *(u16x4*)&outb[(size_t)row * Cpad + c] = o;
        }
    }
}

// ---------------- bf16 MFMA GEMM, 64x64 tile, counted-vmcnt ring pipeline ---
// C = A[M,K] * Bt[N,K]^T + bias. BM=BN=64, BK=64, ring-4 LDS buffers (64 KB),
// 4 waves 2x2, wave tile 32x32 (2x2 frags -> 8 MFMA : 8 ds_read per step).
// Pre-swizzled global_load_lds staging; vmcnt(8/4/0), never 0 mid-loop.
template<int RELU, int WF32, int WBF16, int PHI, int K>
__global__ __launch_bounds__(256) void gemm_bf16_kernel(
    const __hip_bfloat16* __restrict__ A, const __hip_bfloat16* __restrict__ Bt,
    const float* __restrict__ bias,
    float* __restrict__ C, __hip_bfloat16* __restrict__ Cb,
    int N) {
    constexpr int NSTEP = K / 64;
    __shared__ __align__(16) __hip_bfloat16 As[4][64][64];
    __shared__ __align__(16) __hip_bfloat16 Bs[4][64][64];
    const int tid = threadIdx.x, lane = tid & 63, w = tid >> 6;
    const int nN = N >> 6;
    const int bm = (blockIdx.x / nN) * 64;
    const int bn = (blockIdx.x % nN) * 64;

    // staging: instr i of matrix covers rows i*32 + w*8 + (lane>>3), slot lane&7
    const int srow  = lane >> 3;                 // 0..7
    const int sslot = (lane & 7) ^ srow;         // pre-swizzled global slot
    const size_t aoff = (size_t)srow * K + (size_t)sslot * 8;
    const __hip_bfloat16* gA0 = A  + (size_t)(bm + w * 8) * K + aoff;
    const __hip_bfloat16* gA1 = A  + (size_t)(bm + 32 + w * 8) * K + aoff;
    const __hip_bfloat16* gB0 = Bt + (size_t)(bn + w * 8) * K + aoff;
    const __hip_bfloat16* gB1 = Bt + (size_t)(bn + 32 + w * 8) * K + aoff;

#define STAGE(t) do { \
        load_lds16(gA0 + (size_t)(t) * 64, &As[(t) & 3][w * 8][0]); \
        load_lds16(gA1 + (size_t)(t) * 64, &As[(t) & 3][32 + w * 8][0]); \
        load_lds16(gB0 + (size_t)(t) * 64, &Bs[(t) & 3][w * 8][0]); \
        load_lds16(gB1 + (size_t)(t) * 64, &Bs[(t) & 3][32 + w * 8][0]); \
    } while (0)

    const int wm = (w >> 1) << 5, wn = (w & 1) << 5;
    const int fr = lane & 15, fq = lane >> 4;
    const int sw = fr & 7;
    const int e0 = ((fq      ^ sw) << 3);        // k-half 0 slot (swizzled)
    const int e1 = (((fq | 4) ^ sw) << 3);       // k-half 1 slot
    f32x4 acc00 = {0.f, 0.f, 0.f, 0.f}, acc01 = acc00, acc10 = acc00, acc11 = acc00;

    STAGE(0); STAGE(1); STAGE(2);
#pragma unroll
    for (int t = 0; t < NSTEP; ++t) {
        if (NSTEP - t >= 3)      asm volatile("s_waitcnt vmcnt(8)" ::: "memory");
        else if (NSTEP - t == 2) asm volatile("s_waitcnt vmcnt(4)" ::: "memory");
        else                     asm volatile("s_waitcnt vmcnt(0)" ::: "memory");
        __builtin_amdgcn_s_barrier();
        __builtin_amdgcn_sched_barrier(0);
        if (t + 3 < NSTEP) STAGE(t + 3);
        const int b = t & 3;
        bf16x8 a00 = *(const bf16x8*)&As[b][wm + fr][e0];
        bf16x8 a01 = *(const bf16x8*)&As[b][wm + fr][e1];
        bf16x8 a10 = *(const bf16x8*)&As[b][wm + 16 + fr][e0];
        bf16x8 a11 = *(const bf16x8*)&As[b][wm + 16 + fr][e1];
        bf16x8 b00 = *(const bf16x8*)&Bs[b][wn + fr][e0];
        bf16x8 b01 = *(const bf16x8*)&Bs[b][wn + fr][e1];
        bf16x8 b10 = *(const bf16x8*)&Bs[b][wn + 16 + fr][e0];
        bf16x8 b11 = *(const bf16x8*)&Bs[b][wn + 16 + fr][e1];
        acc00 = MFMA_BF16(a00, b00, acc00, 0, 0, 0);
        acc01 = MFMA_BF16(a00, b10, acc01, 0, 0, 0);
        acc10 = MFMA_BF16(a10, b00, acc10, 0, 0, 0);
        acc11 = MFMA_BF16(a10, b10, acc11, 0, 0, 0);
        acc00 = MFMA_BF16(a01, b01, acc00, 0, 0, 0);
        acc01 = MFMA_BF16(a01, b11, acc01, 0, 0, 0);
        acc10 = MFMA_BF16(a11, b01, acc10, 0, 0, 0);
        acc11 = MFMA_BF16(a11, b11, acc11, 0, 0, 0);
    }
#undef STAGE

    const int orow = bm + wm + (fq << 2);
    const int ocol = bn + wn + fr;
    float bv0 = bias[ocol], bv1 = bias[ocol + 16];
    f32x4 accs[2][2] = {{acc00, acc01}, {acc10, acc11}};
#pragma unroll
    for (int i = 0; i < 2; ++i)
#pragma unroll
        for (int r = 0; r < 4; ++r) {
            int row = orow + i * 16 + r;
            float v0 = accs[i][0][r] + bv0;
            float v1 = accs[i][1][r] + bv1;
            if (RELU) { v0 = fmaxf(v0, 0.f); v1 = fmaxf(v1, 0.f); }
            if (PHI) {
                if (ocol < 1024)      v0 = phi(v0);
                if (ocol + 16 < 1024) v1 = phi(v1);
            }
            if (WF32) {
                C[(size_t)row * N + ocol]      = v0;
                C[(size_t)row * N + ocol + 16] = v1;
            }
            if (WBF16) {
                Cb[(size_t)row * N + ocol]      = __float2bfloat16(v0);
                Cb[(size_t)row * N + ocol + 16] = __float2bfloat16(v1);
            }
        }
}

// ---------------- weight transpose + bf16 convert (+ qkv bias concat) -------
__global__ __launch_bounds__(256) void wconv_kernel(
    const float* __restrict__ W_pre, const float* __restrict__ Wq,
    const float* __restrict__ Wk, const float* __restrict__ Wv,
    const float* __restrict__ Wo, const float* __restrict__ W1,
    const float* __restrict__ W2, const float* __restrict__ W_post,
    const float* __restrict__ bq, const float* __restrict__ bk,
    const float* __restrict__ bv, float* __restrict__ qkvbias,
    __hip_bfloat16* wpre_t, __hip_bfloat16* wqkv_t, __hip_bfloat16* wo_t,
    __hip_bfloat16* w1_t, __hip_bfloat16* w2_t, __hip_bfloat16* wpost_t) {
    __shared__ float tile[64][65];
    int tb = blockIdx.x;
    if (tb >= 2400) {               // qkv bias concat: 6 blocks
        int l = tb - 2400;
        for (int i = threadIdx.x; i < 512; i += 256) {
            qkvbias[l * QKVLD + i]        = bq[l * DMODEL + i];
            qkvbias[l * QKVLD + 512 + i]  = bk[l * DMODEL + i];
            qkvbias[l * QKVLD + 1024 + i] = bv[l * DMODEL + i];
        }
        return;
    }
    const float* src; __hip_bfloat16* dst; int K, Kpad, kt, nt;
    if (tb < 32) {
        src = W_pre; dst = wpre_t; K = FIN; Kpad = FINPAD;
        kt = tb >> 3; nt = tb & 7;
    } else {
        int t2 = tb - 32; int mat = t2 >> 6; int tt = t2 & 63;
        kt = tt >> 3; nt = tt & 7; K = 512; Kpad = 512;
        if (mat == 36) { src = W_post; dst = wpost_t; }
        else {
            int l = mat / 6, j = mat % 6;
            const size_t WSZ = 262144;
            switch (j) {
                case 0: src = Wq + l * WSZ; dst = wqkv_t + l * 786432;          break;
                case 1: src = Wk + l * WSZ; dst = wqkv_t + l * 786432 + 262144; break;
                case 2: src = Wv + l * WSZ; dst = wqkv_t + l * 786432 + 524288; break;
                case 3: src = Wo + l * WSZ; dst = wo_t + l * WSZ;               break;
                case 4: src = W1 + l * WSZ; dst = w1_t + l * WSZ;               break;
                default: src = W2 + l * WSZ; dst = w2_t + l * WSZ;              break;
            }
        }
    }
    const int N = 512;
    int t = threadIdx.x;
    int k0 = kt * 64, n0 = nt * 64;
#pragma unroll
    for (int i = 0; i < 16; ++i) {
        int kk = (t >> 6) * 16 + i;
        int nn = t & 63;
        int k = k0 + kk;
        tile[kk][nn] = (k < K) ? src[(size_t)k * N + n0 + nn] : 0.f;
    }
    __syncthreads();
#pragma unroll
    for (int i = 0; i < 16; ++i) {
        int nn = (t >> 6) * 16 + i;
        int kk = t & 63;
        dst[(size_t)(n0 + nn) * Kpad + k0 + kk] = __float2bfloat16(tile[kk][nn]);
    }
}

// ---------------- attention phase A: S_c = V^T K (32x32, bf16 out) + ksum --
// grid (NCHUNK, NHEAD, B), 64 threads. qkvb: bf16 [2048][1536], Q|phi, K|phi, V.
__global__ __launch_bounds__(64) void attn_state_kernel(
    const __hip_bfloat16* __restrict__ qkvb,
    __hip_bfloat16* __restrict__ Sg, float* __restrict__ ksumg) {
    __shared__ __hip_bfloat16 Kt[32][72];
    __shared__ __hip_bfloat16 Vt[32][72];
    int c = blockIdx.x, hh = blockIdx.y, b = blockIdx.z;
    int t = threadIdx.x;
    int sub = t >> 2, slot = t & 3;
    size_t rb = ((size_t)(b * SEQ + c * CHUNK)) * QKVLD + hh * DHEAD;
#pragma unroll
    for (int it = 0; it < 4; ++it) {
        int s = it * 16 + sub;
        bf16x8 kv = *(const bf16x8*)&qkvb[rb + (size_t)s * QKVLD + 512 + slot * 8];
        bf16x8 vv = *(const bf16x8*)&qkvb[rb + (size_t)s * QKVLD + 1024 + slot * 8];
#pragma unroll
        for (int i = 0; i < 8; ++i) {
            Kt[slot * 8 + i][s] = ((const __hip_bfloat16*)&kv)[i];
            Vt[slot * 8 + i][s] = ((const __hip_bfloat16*)&vv)[i];
        }
    }
    __syncthreads();
    int fr = t & 15, fq = t >> 4;
    f32x4 a00 = {0.f,0.f,0.f,0.f}, a01 = a00, a10 = a00, a11 = a00;
#pragma unroll
    for (int ks = 0; ks < 2; ++ks) {
        bf16x8 v0 = *(const bf16x8*)&Vt[fr][ks * 32 + fq * 8];
        bf16x8 v1 = *(const bf16x8*)&Vt[16 + fr][ks * 32 + fq * 8];
        bf16x8 k0 = *(const bf16x8*)&Kt[fr][ks * 32 + fq * 8];
        bf16x8 k1 = *(const bf16x8*)&Kt[16 + fr][ks * 32 + fq * 8];
        a00 = MFMA_BF16(v0, k0, a00, 0, 0, 0);
        a01 = MFMA_BF16(v0, k1, a01, 0, 0, 0);
        a10 = MFMA_BF16(v1, k0, a10, 0, 0, 0);
        a11 = MFMA_BF16(v1, k1, a11, 0, 0, 0);
    }
    size_t ob = ((size_t)((b * NHEAD + hh) * NCHUNK + c)) * 1024;
#pragma unroll
    for (int r = 0; r < 4; ++r) {
        int m0 = fq * 4 + r;
        Sg[ob + (size_t)m0 * 32 + fr]             = __float2bfloat16(a00[r]);
        Sg[ob + (size_t)m0 * 32 + 16 + fr]        = __float2bfloat16(a01[r]);
        Sg[ob + (size_t)(16 + m0) * 32 + fr]      = __float2bfloat16(a10[r]);
        Sg[ob + (size_t)(16 + m0) * 32 + 16 + fr] = __float2bfloat16(a11[r]);
    }
    if (t < 32) {
        float s_ = 0.f;
        for (int s = 0; s < CHUNK; ++s) s_ += __bfloat162float(Kt[t][s]);
        ksumg[((size_t)((b * NHEAD + hh) * NCHUNK + c)) * 32 + t] = s_;
    }
}

// ---------------- attention phase B: intra-chunk (MFMA) + state + output ---
// grid (NCHUNK, NHEAD, B), 256 threads (4 waves; wave w owns rows w*16..+15).
__global__ __launch_bounds__(256) void attn_out_kernel(
    const __hip_bfloat16* __restrict__ qkvb,
    const __hip_bfloat16* __restrict__ Sg, const float* __restrict__ ksumg,
    __hip_bfloat16* __restrict__ out) {
    __shared__ __hip_bfloat16 Qs[64][40];
    __shared__ __hip_bfloat16 Ks[64][40];
    __shared__ __hip_bfloat16 Vt[32][72];
    __shared__ __hip_bfloat16 Awb[64][72];
    __shared__ __hip_bfloat16 Stb[32][40];
    __shared__ float den[64];
    __shared__ float ksml[32];
    int c = blockIdx.x, hh = blockIdx.y, b = blockIdx.z;
    int tid = threadIdx.x, lane = tid & 63, w = tid >> 6;
    size_t rb = ((size_t)(b * SEQ + c * CHUNK)) * QKVLD + hh * DHEAD;
    {
        int row = tid >> 2, slot = tid & 3;
        *(bf16x8*)&Qs[row][slot * 8] =
            *(const bf16x8*)&qkvb[rb + (size_t)row * QKVLD + slot * 8];
        *(bf16x8*)&Ks[row][slot * 8] =
            *(const bf16x8*)&qkvb[rb + (size_t)row * QKVLD + 512 + slot * 8];
        bf16x8 vv = *(const bf16x8*)&qkvb[rb + (size_t)row * QKVLD + 1024 + slot * 8];
#pragma unroll
        for (int i = 0; i < 8; ++i)
            Vt[slot * 8 + i][row] = ((const __hip_bfloat16*)&vv)[i];
    }
    // state prefix (sum of prior chunks' S, bf16 chunks, fp32 accumulate)
    size_t sb = ((size_t)((b * NHEAD + hh) * NCHUNK)) * 1024;
    {
        f32x4 st = {0.f, 0.f, 0.f, 0.f};
        for (int cp = 0; cp < c; ++cp) {
            u16x4 sv = *(const u16x4*)&Sg[sb + (size_t)cp * 1024 + tid * 4];
#pragma unroll
            for (int i = 0; i < 4; ++i) st[i] += bf2f(sv[i]);
        }
        int m = tid >> 3, d0 = (tid & 7) * 4;
#pragma unroll
        for (int i = 0; i < 4; ++i) Stb[m][d0 + i] = __float2bfloat16(st[i]);
    }
    if (tid < 32) {
        size_t kb = ((size_t)((b * NHEAD + hh) * NCHUNK)) * 32;
        float s_ = 0.f;
        for (int cp = 0; cp < c; ++cp) s_ += ksumg[kb + cp * 32 + tid];
        ksml[tid] = s_;
    }
    __syncthreads();
    int fr = lane & 15, fq = lane >> 4;
    bf16x8 aQ = *(const bf16x8*)&Qs[w * 16 + fr][fq * 8];
    f32x4 p[4];
#pragma unroll
    for (int j = 0; j < 4; ++j) {
        f32x4 z = {0.f, 0.f, 0.f, 0.f};
        bf16x8 bK = *(const bf16x8*)&Ks[j * 16 + fr][fq * 8];
        p[j] = MFMA_BF16(aQ, bK, z, 0, 0, 0);
    }
    // causal mask + row sums (denominator, fp32)
    float rs[4] = {0.f, 0.f, 0.f, 0.f};
#pragma unroll
    for (int j = 0; j < 4; ++j) {
        int tcol = j * 16 + fr;
#pragma unroll
        for (int r = 0; r < 4; ++r) {
            int s = w * 16 + fq * 4 + r;
            float val = (tcol <= s) ? p[j][r] : 0.f;
            p[j][r] = val;
            rs[r] += val;
        }
    }
#pragma unroll
    for (int off = 8; off > 0; off >>= 1) {
#pragma unroll
        for (int r = 0; r < 4; ++r) rs[r] += __shfl_xor(rs[r], off, 64);
    }
    if (fr == 0) {
#pragma unroll
        for (int r = 0; r < 4; ++r) den[w * 16 + fq * 4 + r] = rs[r];
    }
#pragma unroll
    for (int j = 0; j < 4; ++j)
#pragma unroll
        for (int r = 0; r < 4; ++r)
            Awb[w * 16 + fq * 4 + r][j * 16 + fr] = __float2bfloat16(p[j][r]);
    __syncthreads();
    if (tid < 64) {
        float dq = den[tid];
        float dst_ = 0.f;
#pragma unroll
        for (int d = 0; d < 32; ++d)
            dst_ += __bfloat162float(Qs[tid][d]) * ksml[d];
        den[tid] = 1.f / (dq + dst_ + 1e-6f);
    }
    __syncthreads();
    size_t orb = ((size_t)(b * SEQ + c * CHUNK)) * DMODEL + hh * DHEAD;
#pragma unroll
    for (int mf = 0; mf < 2; ++mf) {
        f32x4 acc = {0.f, 0.f, 0.f, 0.f};
        bf16x8 bS = *(const bf16x8*)&Stb[mf * 16 + fr][fq * 8];
        acc = MFMA_BF16(aQ, bS, acc, 0, 0, 0);
#pragma unroll
        for (int ks = 0; ks < 2; ++ks) {
            bf16x8 aA = *(const bf16x8*)&Awb[w * 16 + fr][ks * 32 + fq * 8];
            bf16x8 bV = *(const bf16x8*)&Vt[mf * 16 + fr][ks * 32 + fq * 8];
            acc = MFMA_BF16(aA, bV, acc, 0, 0, 0);
        }
#pragma unroll
        for (int r = 0; r < 4; ++r) {
            int s = w * 16 + fq * 4 + r;
            out[orb + (size_t)s * DMODEL + mf * 16 + fr] =
                __float2bfloat16(acc[r] * den[s]);
        }
    }
}

// ---------------------------------------------------------------------------
template<int R, int WF, int WB, int PHI, int K>
static inline void gemm(const __hip_bfloat16* A, const __hip_bfloat16* Bt,
                        const float* bias, float* C, __hip_bfloat16* Cb,
                        int M, int N, hipStream_t s) {
    gemm_bf16_kernel<R, WF, WB, PHI, K><<<(M / 64) * (N / 64), 256, 0, s>>>(A, Bt, bias, C, Cb, N);
}

extern "C" void kernel_launch(void* const* d_in, const int* in_sizes, int n_in,
                              void* d_out, int out_size, void* d_ws, size_t ws_size,
                              hipStream_t stream) {
    const float* x      = (const float*)d_in[0];
    const float* g_in   = (const float*)d_in[1];
    const float* b_in   = (const float*)d_in[2];
    const float* W_pre  = (const float*)d_in[3];
    const float* b_pre  = (const float*)d_in[4];
    const float* Wq     = (const float*)d_in[5];
    const float* bq     = (const float*)d_in[6];
    const float* Wk     = (const float*)d_in[7];
    const float* bk     = (const float*)d_in[8];
    const float* Wv     = (const float*)d_in[9];
    const float* bv     = (const float*)d_in[10];
    const float* Wo     = (const float*)d_in[11];
    const float* bo     = (const float*)d_in[12];
    const float* W1     = (const float*)d_in[13];
    const float* bf1    = (const float*)d_in[14];
    const float* W2     = (const float*)d_in[15];
    const float* bf2    = (const float*)d_in[16];
    const float* ln1_g  = (const float*)d_in[17];
    const float* ln1_b  = (const float*)d_in[18];
    const float* ln2_g  = (const float*)d_in[19];
    const float* ln2_b  = (const float*)d_in[20];
    const float* lnf_g  = (const float*)d_in[21];
    const float* lnf_b  = (const float*)d_in[22];
    const float* W_post = (const float*)d_in[23];
    const float* b_post = (const float*)d_in[24];
    (void)in_sizes; (void)n_in; (void)out_size; (void)ws_size;

    float* ws = (float*)d_ws;
    const size_t SZ = (size_t)NROW * DMODEL;          // 1048576
    float* h       = ws;
    float* t1      = h + SZ;
    float* ksumg   = t1 + SZ;                         // 16384
    float* qkvbias = ksumg + 16384;                   // 9216
    __hip_bfloat16* bp = (__hip_bfloat16*)(qkvbias + 9216);
    __hip_bfloat16* Sg     = bp;            bp += 524288;                  // bf16 state chunks
    __hip_bfloat16* hb     = bp;            bp += SZ;
    __hip_bfloat16* qkvb   = bp;            bp += (size_t)NROW * QKVLD;    // 3145728
    __hip_bfloat16* xnb    = bp;            bp += (size_t)NROW * FINPAD;   // 524288
    __hip_bfloat16* attb   = bp;            bp += SZ;
    __hip_bfloat16* ffb    = bp;            bp += SZ;
    __hip_bfloat16* t0b    = bp;            bp += SZ;
    __hip_bfloat16* wpre_t = bp;            bp += (size_t)DMODEL * FINPAD; // 131072
    __hip_bfloat16* wqkv_t = bp;            bp += (size_t)NLAYER * 786432;
    __hip_bfloat16* wo_t   = bp;            bp += (size_t)NLAYER * 262144;
    __hip_bfloat16* w1_t   = bp;            bp += (size_t)NLAYER * 262144;
    __hip_bfloat16* w2_t   = bp;            bp += (size_t)NLAYER * 262144;
    __hip_bfloat16* wpost_t= bp;

    // one-time-per-call weight conversion + qkv bias concat
    wconv_kernel<<<2406, 256, 0, stream>>>(
        W_pre, Wq, Wk, Wv, Wo, W1, W2, W_post,
        bq, bk, bv, qkvbias,
        wpre_t, wqkv_t, wo_t, w1_t, w2_t, wpost_t);

    // input LN (bf16, K padded 240->256) + pre projection (h fp32 + hb bf16)
    ln_kernel<<<NROW, 64, 0, stream>>>(x, nullptr, g_in, b_in, nullptr, xnb, FIN, FINPAD);
    gemm<0, 1, 1, 0, FINPAD>(xnb, wpre_t, b_pre, h, hb, NROW, DMODEL, stream);

    dim3 ag(NCHUNK, NHEAD, 2);
    for (int l = 0; l < NLAYER; ++l) {
        // fused QKV projection -> bf16 [2048][1536], phi applied to Q,K cols
        gemm<0, 0, 1, 1, DMODEL>(hb, wqkv_t + (size_t)l * 786432, qkvbias + l * QKVLD,
                                 nullptr, qkvb, NROW, QKVLD, stream);
        attn_state_kernel<<<ag, 64, 0, stream>>>(qkvb, Sg, ksumg);
        attn_out_kernel<<<ag, 256, 0, stream>>>(qkvb, Sg, ksumg, attb);
        gemm<0, 1, 0, 0, DMODEL>(attb, wo_t + (size_t)l * 262144, bo + l * DMODEL,
                                 t1, nullptr, NROW, DMODEL, stream);
        ln_kernel<<<NROW, 64, 0, stream>>>(h, t1, ln1_g + l * DMODEL, ln1_b + l * DMODEL,
                                           h, hb, DMODEL, DMODEL);
        gemm<1, 0, 1, 0, DMODEL>(hb, w1_t + (size_t)l * 262144, bf1 + l * DMODEL,
                                 nullptr, ffb, NROW, DMODEL, stream);
        gemm<0, 1, 0, 0, DMODEL>(ffb, w2_t + (size_t)l * 262144, bf2 + l * DMODEL,
                                 t1, nullptr, NROW, DMODEL, stream);
        ln_kernel<<<NROW, 64, 0, stream>>>(h, t1, ln2_g + l * DMODEL, ln2_b + l * DMODEL,
                                           h, hb, DMODEL, DMODEL);
    }

    // final LN (bf16 only) + post projection (fp32 to d_out)
    ln_kernel<<<NROW, 64, 0, stream>>>(h, nullptr, lnf_g, lnf_b, nullptr, t0b, DMODEL, DMODEL);
    gemm<0, 1, 0, 0, DMODEL>(t0b, wpost_t, b_post, (float*)d_out, nullptr, NROW, DMODEL, stream);
}